// Round 1
// baseline (2315.339 us; speedup 1.0000x reference)
//
#include <hip/hip_runtime.h>
#include <cmath>

// DenseRnn on MI355X. Shapes: B=2, N=2048, D=1024, H=8, HD=128.
//
// Pipeline:
//  1. gemm_f32 x@Wq, x@Wk, x@Wv  -> qraw/kraw/vraw  [4096,1024]
//  2. gemm_f32 x@Wf1 -> f1 [4096,128]; x@Wog1 -> og1 [4096,128]
//  3. prep: per (row,h) block of 128 thr: silu(q,v), silu+l2norm(k),
//     beta = 2*sigmoid(x.Wbeta_col) (dot folded in), e = sigmoid(f1.Wf2_col)
//     packed into sb[row,h][640] = {k[128], e[128], q[128], v[128], beta@512}
//  4. scan: per-column recurrence, 16 lanes/column, 8 rows/lane.
//     Per token: S = e*(S + k*(-beta*bS));  S += k*(v_col - beta*kS1); o = q.S
//  5. post: gate = og1@Wog2 (folded), y = o*sigmoid(gate), per-head RMS, *norm_w
//  6. gemm_f32 y@Wo -> d_out
//
// Workspace (floats): qraw[SZ] kraw[SZ] vraw[SZ] sb[5*SZ] ov[SZ] f1[.5M] og1[.5M]
//   total = 9.25*SZ*4B ~= 155 MB

#define SZT ((size_t)4096 * 1024)

__device__ __forceinline__ float sigmf(float x) { return 1.f / (1.f + expf(-x)); }
__device__ __forceinline__ float siluf(float x) { return x * sigmf(x); }

// ---------------- fp32 GEMM: C[M,N] = A[M,K] @ B[K,N], row-major.
// Requires M%64==0, N%64==0, K%16==0.
__global__ __launch_bounds__(256) void gemm_f32(
    const float* __restrict__ A, const float* __restrict__ B, float* __restrict__ C,
    int M, int N, int K)
{
    __shared__ float As[16][64];
    __shared__ float Bs[16][64];
    const int tid = threadIdx.x;
    const int row0 = blockIdx.y * 64;
    const int col0 = blockIdx.x * 64;
    const int tx = tid & 15, ty = tid >> 4;
    const int am = tid >> 2, akc = tid & 3;   // A-load coords: row am, k-chunk akc
    const int bkr = tid >> 4, bnc = tid & 15; // B-load coords: k-row bkr, n-chunk bnc

    float acc[4][4];
#pragma unroll
    for (int i = 0; i < 4; i++)
#pragma unroll
        for (int j = 0; j < 4; j++) acc[i][j] = 0.f;

    for (int k0 = 0; k0 < K; k0 += 16) {
        float4 av = *(const float4*)&A[(size_t)(row0 + am) * K + k0 + akc * 4];
        float4 bv = *(const float4*)&B[(size_t)(k0 + bkr) * N + col0 + bnc * 4];
        As[akc * 4 + 0][am] = av.x;
        As[akc * 4 + 1][am] = av.y;
        As[akc * 4 + 2][am] = av.z;
        As[akc * 4 + 3][am] = av.w;
        *(float4*)&Bs[bkr][bnc * 4] = bv;
        __syncthreads();
#pragma unroll
        for (int kk = 0; kk < 16; kk++) {
            float4 a = *(const float4*)&As[kk][ty * 4];
            float4 b = *(const float4*)&Bs[kk][tx * 4];
            acc[0][0] += a.x * b.x; acc[0][1] += a.x * b.y; acc[0][2] += a.x * b.z; acc[0][3] += a.x * b.w;
            acc[1][0] += a.y * b.x; acc[1][1] += a.y * b.y; acc[1][2] += a.y * b.z; acc[1][3] += a.y * b.w;
            acc[2][0] += a.z * b.x; acc[2][1] += a.z * b.y; acc[2][2] += a.z * b.z; acc[2][3] += a.z * b.w;
            acc[3][0] += a.w * b.x; acc[3][1] += a.w * b.y; acc[3][2] += a.w * b.z; acc[3][3] += a.w * b.w;
        }
        __syncthreads();
    }
#pragma unroll
    for (int i = 0; i < 4; i++) {
        float4 o = make_float4(acc[i][0], acc[i][1], acc[i][2], acc[i][3]);
        *(float4*)&C[(size_t)(row0 + ty * 4 + i) * N + col0 + tx * 4] = o;
    }
}

// ---------------- prep: one block per (row, h), 128 threads.
__global__ __launch_bounds__(128) void prep_kernel(
    const float* __restrict__ x, const float* __restrict__ Wbeta,
    const float* __restrict__ Wf2, const float* __restrict__ f1,
    const float* __restrict__ qraw, const float* __restrict__ kraw,
    const float* __restrict__ vraw, float* __restrict__ sb)
{
    const int gid = blockIdx.x;      // row*8 + h, row in [0,4096)
    const int h = gid & 7;
    const int row = gid >> 3;
    const int tid = threadIdx.x;
    const int col = h * 128 + tid;   // column within D
    const size_t rbase = (size_t)row * 1024;

    __shared__ float f1s[128];
    __shared__ float red[2][128];

    f1s[tid] = f1[(size_t)row * 128 + tid];

    // beta partial dot: x[row,:] . Wbeta[:,h]
    float bsum = 0.f;
#pragma unroll
    for (int i = 0; i < 8; i++)
        bsum += x[rbase + tid + i * 128] * Wbeta[(size_t)(tid + i * 128) * 8 + h];

    // silu(k) and its squared-norm partial
    float kr = kraw[rbase + col];
    float ksil = siluf(kr);

    red[0][tid] = bsum;
    red[1][tid] = ksil * ksil;
    __syncthreads();

    // f dot: f1[row,:] . Wf2[:,col]
    float fsum = 0.f;
#pragma unroll 8
    for (int i = 0; i < 128; i++) fsum += f1s[i] * Wf2[(size_t)i * 1024 + col];

    for (int off = 64; off > 0; off >>= 1) {
        if (tid < off) {
            red[0][tid] += red[0][tid + off];
            red[1][tid] += red[1][tid + off];
        }
        __syncthreads();
    }
    const float beta = 2.f * sigmf(red[0][0]);
    const float rn = rsqrtf(red[1][0] + 1e-6f);

    const float kn = ksil * rn;           // l2-normalized k
    const float e = sigmf(fsum);          // exp(log_sigmoid(f)) = sigmoid(f)
    const float qs = siluf(qraw[rbase + col]);
    const float vs = siluf(vraw[rbase + col]);

    float* o = sb + (size_t)gid * 640;
    o[tid] = kn;
    o[128 + tid] = e;
    o[256 + tid] = qs;
    o[384 + tid] = vs;
    if (tid == 0) o[512] = beta;
}

// ---------------- scan: 128 blocks x 256 threads.
// block -> (bh = blk>>3 in [0,16), cg = blk&7); thread -> column cg*16 + (tid>>4),
// row-group rg = tid&15 owning rows rg*8 .. rg*8+7 of S[:,col].
__global__ __launch_bounds__(256) void scan_kernel(
    const float* __restrict__ sb, float* __restrict__ ov)
{
    const int tid = threadIdx.x;
    const int blk = blockIdx.x;
    const int bh = blk >> 3;
    const int cg = blk & 7;
    const int b = bh >> 3, h = bh & 7;
    const int col = cg * 16 + (tid >> 4);
    const int rg = tid & 15;
    const int ro = rg * 2;   // float4 offset of this lane's 8 rows

    float S0 = 0.f, S1 = 0.f, S2 = 0.f, S3 = 0.f, S4 = 0.f, S5 = 0.f, S6 = 0.f, S7 = 0.f;

    const size_t tokidx0 = (size_t)b * 2048 * 8 + h;   // chunk index = tokidx0 + t*8

    for (int t = 0; t < 2048; ++t) {
        const float* vb = sb + (tokidx0 + (size_t)t * 8) * 640;
        const float4* p4 = (const float4*)vb;

        float4 k0 = p4[ro], k1 = p4[ro + 1];
        float4 e0 = p4[32 + ro], e1 = p4[33 + ro];
        const float beta = vb[512];
        const float vcol = vb[384 + col];

        // phase A: bS = k^T S   (partial over this lane's 8 rows, then 16-lane butterfly)
        float bs = k0.x * S0 + k0.y * S1 + k0.z * S2 + k0.w * S3
                 + k1.x * S4 + k1.y * S5 + k1.z * S6 + k1.w * S7;
        bs += __shfl_xor(bs, 1); bs += __shfl_xor(bs, 2);
        bs += __shfl_xor(bs, 4); bs += __shfl_xor(bs, 8);

        // phase B: S = e .* (S + k * (-beta*bS));  kS1 = k^T S
        const float bb = -beta * bs;
        S0 = e0.x * (S0 + k0.x * bb); S1 = e0.y * (S1 + k0.y * bb);
        S2 = e0.z * (S2 + k0.z * bb); S3 = e0.w * (S3 + k0.w * bb);
        S4 = e1.x * (S4 + k1.x * bb); S5 = e1.y * (S5 + k1.y * bb);
        S6 = e1.z * (S6 + k1.z * bb); S7 = e1.w * (S7 + k1.w * bb);
        float ks = k0.x * S0 + k0.y * S1 + k0.z * S2 + k0.w * S3
                 + k1.x * S4 + k1.y * S5 + k1.z * S6 + k1.w * S7;
        ks += __shfl_xor(ks, 1); ks += __shfl_xor(ks, 2);
        ks += __shfl_xor(ks, 4); ks += __shfl_xor(ks, 8);

        // phase C: S += k * (v_col - beta*kS1);  o = q^T S
        const float w = vcol - beta * ks;
        float4 q0 = p4[64 + ro], q1 = p4[65 + ro];
        S0 += k0.x * w; S1 += k0.y * w; S2 += k0.z * w; S3 += k0.w * w;
        S4 += k1.x * w; S5 += k1.y * w; S6 += k1.z * w; S7 += k1.w * w;
        float o = q0.x * S0 + q0.y * S1 + q0.z * S2 + q0.w * S3
                + q1.x * S4 + q1.y * S5 + q1.z * S6 + q1.w * S7;
        o += __shfl_xor(o, 1); o += __shfl_xor(o, 2);
        o += __shfl_xor(o, 4); o += __shfl_xor(o, 8);

        if (rg == 0) ov[(tokidx0 + (size_t)t * 8) * 128 + col] = o;
    }
}

// ---------------- post: one block per (row, h), 128 threads.
// gate = og1[row,:] @ Wog2[:,col]; y = o*sigmoid(gate); per-head RMS; *norm_w
__global__ __launch_bounds__(128) void post_kernel(
    const float* __restrict__ ov, const float* __restrict__ og1,
    const float* __restrict__ Wog2, const float* __restrict__ normw,
    float* __restrict__ ybuf)
{
    const int gid = blockIdx.x;
    const int h = gid & 7;
    const int row = gid >> 3;
    const int tid = threadIdx.x;
    const int col = h * 128 + tid;

    __shared__ float ogs[128];
    __shared__ float red[128];

    ogs[tid] = og1[(size_t)row * 128 + tid];
    __syncthreads();

    float g = 0.f;
#pragma unroll 8
    for (int i = 0; i < 128; i++) g += ogs[i] * Wog2[(size_t)i * 1024 + col];

    const float o = ov[(size_t)row * 1024 + col];
    const float y = o * sigmf(g);

    red[tid] = y * y;
    __syncthreads();
    for (int off = 64; off > 0; off >>= 1) {
        if (tid < off) red[tid] += red[tid + off];
        __syncthreads();
    }
    const float rms = rsqrtf(red[0] * (1.f / 128.f) + 1e-6f);
    ybuf[(size_t)row * 1024 + col] = y * rms * normw[col];
}

extern "C" void kernel_launch(void* const* d_in, const int* in_sizes, int n_in,
                              void* d_out, int out_size, void* d_ws, size_t ws_size,
                              hipStream_t stream)
{
    const float* x     = (const float*)d_in[0];
    const float* Wq    = (const float*)d_in[1];
    const float* Wk    = (const float*)d_in[2];
    const float* Wv    = (const float*)d_in[3];
    const float* Wf1   = (const float*)d_in[4];
    const float* Wf2   = (const float*)d_in[5];
    const float* Wbeta = (const float*)d_in[6];
    const float* Wog1  = (const float*)d_in[7];
    const float* Wog2  = (const float*)d_in[8];
    const float* normw = (const float*)d_in[9];
    const float* Wo    = (const float*)d_in[10];
    float* out = (float*)d_out;

    float* ws   = (float*)d_ws;
    float* qraw = ws;
    float* kraw = ws + SZT;
    float* vraw = ws + 2 * SZT;
    float* sb   = ws + 3 * SZT;          // 5*SZT floats
    float* ov   = ws + 8 * SZT;
    float* f1   = ws + 9 * SZT;          // 4096*128
    float* og1  = f1 + (size_t)4096 * 128;
    float* ybuf = qraw;                  // reuse (qraw dead after prep)

    dim3 b256(256), b128(128);

    gemm_f32<<<dim3(16, 64), b256, 0, stream>>>(x, Wq, qraw, 4096, 1024, 1024);
    gemm_f32<<<dim3(16, 64), b256, 0, stream>>>(x, Wk, kraw, 4096, 1024, 1024);
    gemm_f32<<<dim3(16, 64), b256, 0, stream>>>(x, Wv, vraw, 4096, 1024, 1024);
    gemm_f32<<<dim3(2, 64),  b256, 0, stream>>>(x, Wf1, f1,  4096, 128, 1024);
    gemm_f32<<<dim3(2, 64),  b256, 0, stream>>>(x, Wog1, og1, 4096, 128, 1024);

    prep_kernel<<<32768, b128, 0, stream>>>(x, Wbeta, Wf2, f1, qraw, kraw, vraw, sb);
    scan_kernel<<<128, b256, 0, stream>>>(sb, ov);
    post_kernel<<<32768, b128, 0, stream>>>(ov, og1, Wog2, normw, ybuf);

    gemm_f32<<<dim3(16, 64), b256, 0, stream>>>(ybuf, Wo, out, 4096, 1024, 1024);
}

// Round 2
// 1866.330 us; speedup vs baseline: 1.2406x; 1.2406x over previous
//
#include <hip/hip_runtime.h>
#include <cmath>

// DenseRnn on MI355X. Shapes: B=2, N=2048, D=1024, H=8, HD=128.
//
// Pipeline:
//  1. gemm_f32 x@Wq, x@Wk, x@Wv -> qraw/kraw/vraw [4096,1024]
//  2. gemm_f32 x@Wf1 -> f1 [4096,128]; x@Wog1 -> og1 [4096,128]
//  3. prep: per (row,h): silu, l2norm(k), beta, e=sigmoid(f); pack record
//     sb[row*8+h][656] = {k[128], e[128], ke[128], qe[128], v[128],
//                         scalars@640: beta, c=sum(e k^2), d1=sum(q e k), d2=sum(q k)}
//  4. scan: per-column recurrence with fused per-token step:
//     bS=k^T S; kS1=ke^T S - b*bS*c; w=v - b*kS1;
//     o = qe^T S - b*bS*d1 + w*d2;  S' = e.*S - b*bS*ke + w*k
//     All three dots taken against S_prev concurrently; reg-prefetched records.
//  5. post: gate = og1@Wog2, y = o*sigmoid(gate), per-head RMS, *norm_w
//  6. gemm_f32 y@Wo -> d_out

#define SZT ((size_t)4096 * 1024)
#define RECF 656           // floats per (token,b,h) record
#define RECSTRIDE 5248     // floats between consecutive tokens of same (b,h): 8*RECF

__device__ __forceinline__ float sigmf(float x) { return 1.f / (1.f + expf(-x)); }
__device__ __forceinline__ float siluf(float x) { return x * sigmf(x); }

// ---------------- fp32 GEMM: C[M,N] = A[M,K] @ B[K,N], row-major.
__global__ __launch_bounds__(256) void gemm_f32(
    const float* __restrict__ A, const float* __restrict__ B, float* __restrict__ C,
    int M, int N, int K)
{
    __shared__ float As[16][64];
    __shared__ float Bs[16][64];
    const int tid = threadIdx.x;
    const int row0 = blockIdx.y * 64;
    const int col0 = blockIdx.x * 64;
    const int tx = tid & 15, ty = tid >> 4;
    const int am = tid >> 2, akc = tid & 3;
    const int bkr = tid >> 4, bnc = tid & 15;

    float acc[4][4];
#pragma unroll
    for (int i = 0; i < 4; i++)
#pragma unroll
        for (int j = 0; j < 4; j++) acc[i][j] = 0.f;

    for (int k0 = 0; k0 < K; k0 += 16) {
        float4 av = *(const float4*)&A[(size_t)(row0 + am) * K + k0 + akc * 4];
        float4 bv = *(const float4*)&B[(size_t)(k0 + bkr) * N + col0 + bnc * 4];
        As[akc * 4 + 0][am] = av.x;
        As[akc * 4 + 1][am] = av.y;
        As[akc * 4 + 2][am] = av.z;
        As[akc * 4 + 3][am] = av.w;
        *(float4*)&Bs[bkr][bnc * 4] = bv;
        __syncthreads();
#pragma unroll
        for (int kk = 0; kk < 16; kk++) {
            float4 a = *(const float4*)&As[kk][ty * 4];
            float4 b = *(const float4*)&Bs[kk][tx * 4];
            acc[0][0] += a.x * b.x; acc[0][1] += a.x * b.y; acc[0][2] += a.x * b.z; acc[0][3] += a.x * b.w;
            acc[1][0] += a.y * b.x; acc[1][1] += a.y * b.y; acc[1][2] += a.y * b.z; acc[1][3] += a.y * b.w;
            acc[2][0] += a.z * b.x; acc[2][1] += a.z * b.y; acc[2][2] += a.z * b.z; acc[2][3] += a.z * b.w;
            acc[3][0] += a.w * b.x; acc[3][1] += a.w * b.y; acc[3][2] += a.w * b.z; acc[3][3] += a.w * b.w;
        }
        __syncthreads();
    }
#pragma unroll
    for (int i = 0; i < 4; i++) {
        float4 o = make_float4(acc[i][0], acc[i][1], acc[i][2], acc[i][3]);
        *(float4*)&C[(size_t)(row0 + ty * 4 + i) * N + col0 + tx * 4] = o;
    }
}

// ---------------- prep: one block per (row, h), 128 threads.
__global__ __launch_bounds__(128) void prep_kernel(
    const float* __restrict__ x, const float* __restrict__ Wbeta,
    const float* __restrict__ Wf2, const float* __restrict__ f1,
    const float* __restrict__ qraw, const float* __restrict__ kraw,
    const float* __restrict__ vraw, float* __restrict__ sb)
{
    const int gid = blockIdx.x;      // row*8 + h
    const int h = gid & 7;
    const int row = gid >> 3;
    const int tid = threadIdx.x;
    const int col = h * 128 + tid;
    const size_t rbase = (size_t)row * 1024;

    __shared__ float f1s[128];
    __shared__ float red[3][128];

    f1s[tid] = f1[(size_t)row * 128 + tid];

    float bsum = 0.f;
#pragma unroll
    for (int i = 0; i < 8; i++)
        bsum += x[rbase + tid + i * 128] * Wbeta[(size_t)(tid + i * 128) * 8 + h];

    float kr = kraw[rbase + col];
    float ksil = siluf(kr);

    red[0][tid] = bsum;
    red[1][tid] = ksil * ksil;
    __syncthreads();

    float fsum = 0.f;
#pragma unroll 8
    for (int i = 0; i < 128; i++) fsum += f1s[i] * Wf2[(size_t)i * 1024 + col];

    for (int off = 64; off > 0; off >>= 1) {
        if (tid < off) {
            red[0][tid] += red[0][tid + off];
            red[1][tid] += red[1][tid + off];
        }
        __syncthreads();
    }
    const float beta = 2.f * sigmf(red[0][0]);
    const float rn = rsqrtf(red[1][0] + 1e-6f);
    __syncthreads();   // all reads of red[*][0] done before reuse

    const float kn = ksil * rn;
    const float e  = sigmf(fsum);
    const float qs = siluf(qraw[rbase + col]);
    const float vs = siluf(vraw[rbase + col]);
    const float kev = e * kn;
    const float qev = e * qs;

    red[0][tid] = kev * kn;   // -> c  = sum(e k^2)
    red[1][tid] = qs * kev;   // -> d1 = sum(q e k)
    red[2][tid] = qs * kn;    // -> d2 = sum(q k)
    __syncthreads();
    for (int off = 64; off > 0; off >>= 1) {
        if (tid < off) {
            red[0][tid] += red[0][tid + off];
            red[1][tid] += red[1][tid + off];
            red[2][tid] += red[2][tid + off];
        }
        __syncthreads();
    }

    float* o = sb + (size_t)gid * RECF;
    o[tid]        = kn;
    o[128 + tid]  = e;
    o[256 + tid]  = kev;
    o[384 + tid]  = qev;
    o[512 + tid]  = vs;
    if (tid == 0) {
        o[640] = beta;
        o[641] = red[0][0];
        o[642] = red[1][0];
        o[643] = red[2][0];
    }
}

// ---------------- scan
struct TokRegs {
    float4 k0, k1, e0, e1, ke0, ke1, qe0, qe1, sc;
    float vc;
};

__device__ __forceinline__ void load_tok(const float* __restrict__ vb, int ro, int col, TokRegs& T)
{
    const float4* p4 = (const float4*)vb;
    T.k0 = p4[ro];       T.k1 = p4[ro + 1];
    T.e0 = p4[32 + ro];  T.e1 = p4[33 + ro];
    T.ke0 = p4[64 + ro]; T.ke1 = p4[65 + ro];
    T.qe0 = p4[96 + ro]; T.qe1 = p4[97 + ro];
    T.sc = p4[160];
    T.vc = vb[512 + col];
}

#define SCAN_STEP(T, OUTIDX)                                                          \
  {                                                                                   \
    float bS  = ((T.k0.x * S0 + T.k0.y * S1) + (T.k0.z * S2 + T.k0.w * S3))           \
              + ((T.k1.x * S4 + T.k1.y * S5) + (T.k1.z * S6 + T.k1.w * S7));          \
    float keS = ((T.ke0.x * S0 + T.ke0.y * S1) + (T.ke0.z * S2 + T.ke0.w * S3))       \
              + ((T.ke1.x * S4 + T.ke1.y * S5) + (T.ke1.z * S6 + T.ke1.w * S7));      \
    float qeS = ((T.qe0.x * S0 + T.qe0.y * S1) + (T.qe0.z * S2 + T.qe0.w * S3))       \
              + ((T.qe1.x * S4 + T.qe1.y * S5) + (T.qe1.z * S6 + T.qe1.w * S7));      \
    bS += __shfl_xor(bS, 1); keS += __shfl_xor(keS, 1); qeS += __shfl_xor(qeS, 1);    \
    bS += __shfl_xor(bS, 2); keS += __shfl_xor(keS, 2); qeS += __shfl_xor(qeS, 2);    \
    bS += __shfl_xor(bS, 4); keS += __shfl_xor(keS, 4); qeS += __shfl_xor(qeS, 4);    \
    bS += __shfl_xor(bS, 8); keS += __shfl_xor(keS, 8); qeS += __shfl_xor(qeS, 8);    \
    const float bSb = T.sc.x * bS;                                                    \
    const float ks  = keS - bSb * T.sc.y;                                             \
    const float w   = T.vc - T.sc.x * ks;                                             \
    const float o   = (qeS - bSb * T.sc.z) + w * T.sc.w;                              \
    S0 = (T.e0.x * S0 - bSb * T.ke0.x) + w * T.k0.x;                                  \
    S1 = (T.e0.y * S1 - bSb * T.ke0.y) + w * T.k0.y;                                  \
    S2 = (T.e0.z * S2 - bSb * T.ke0.z) + w * T.k0.z;                                  \
    S3 = (T.e0.w * S3 - bSb * T.ke0.w) + w * T.k0.w;                                  \
    S4 = (T.e1.x * S4 - bSb * T.ke1.x) + w * T.k1.x;                                  \
    S5 = (T.e1.y * S5 - bSb * T.ke1.y) + w * T.k1.y;                                  \
    S6 = (T.e1.z * S6 - bSb * T.ke1.z) + w * T.k1.z;                                  \
    S7 = (T.e1.w * S7 - bSb * T.ke1.w) + w * T.k1.w;                                  \
    if (rg == 0) ov[OUTIDX] = o;                                                      \
  }

// 256 blocks x 128 threads. block -> (bh = blk>>4, cg = blk&15); 8 cols/block,
// 16 lanes/col, each lane owns 8 state rows.
__global__ __launch_bounds__(128) void scan_kernel(
    const float* __restrict__ sb, float* __restrict__ ov)
{
    const int tid = threadIdx.x;
    const int blk = blockIdx.x;
    const int bh = blk >> 4;
    const int cg = blk & 15;
    const int b = bh >> 3, h = bh & 7;
    const int col = cg * 8 + (tid >> 4);
    const int rg = tid & 15;
    const int ro = rg * 2;

    float S0 = 0.f, S1 = 0.f, S2 = 0.f, S3 = 0.f, S4 = 0.f, S5 = 0.f, S6 = 0.f, S7 = 0.f;

    const size_t base = (size_t)b * 2048 * 8 + h;
    const float* pa = sb + base * RECF;
    size_t oidx = base * 128 + col;

    TokRegs A, B;
    load_tok(pa, ro, col, A);

    for (int t = 0; t < 2048; t += 2) {
        load_tok(pa + RECSTRIDE, ro, col, B);
        SCAN_STEP(A, oidx);
        const float* pn = (t + 2 < 2048) ? (pa + 2 * RECSTRIDE) : pa;
        load_tok(pn, ro, col, A);
        SCAN_STEP(B, oidx + 1024);
        pa += 2 * RECSTRIDE;
        oidx += 2048;
    }
}

// ---------------- post
__global__ __launch_bounds__(128) void post_kernel(
    const float* __restrict__ ov, const float* __restrict__ og1,
    const float* __restrict__ Wog2, const float* __restrict__ normw,
    float* __restrict__ ybuf)
{
    const int gid = blockIdx.x;
    const int h = gid & 7;
    const int row = gid >> 3;
    const int tid = threadIdx.x;
    const int col = h * 128 + tid;

    __shared__ float ogs[128];
    __shared__ float red[128];

    ogs[tid] = og1[(size_t)row * 128 + tid];
    __syncthreads();

    float g = 0.f;
#pragma unroll 8
    for (int i = 0; i < 128; i++) g += ogs[i] * Wog2[(size_t)i * 1024 + col];

    const float o = ov[(size_t)row * 1024 + col];
    const float y = o * sigmf(g);

    red[tid] = y * y;
    __syncthreads();
    for (int off = 64; off > 0; off >>= 1) {
        if (tid < off) red[tid] += red[tid + off];
        __syncthreads();
    }
    const float rms = rsqrtf(red[0] * (1.f / 128.f) + 1e-6f);
    ybuf[(size_t)row * 1024 + col] = y * rms * normw[col];
}

extern "C" void kernel_launch(void* const* d_in, const int* in_sizes, int n_in,
                              void* d_out, int out_size, void* d_ws, size_t ws_size,
                              hipStream_t stream)
{
    const float* x     = (const float*)d_in[0];
    const float* Wq    = (const float*)d_in[1];
    const float* Wk    = (const float*)d_in[2];
    const float* Wv    = (const float*)d_in[3];
    const float* Wf1   = (const float*)d_in[4];
    const float* Wf2   = (const float*)d_in[5];
    const float* Wbeta = (const float*)d_in[6];
    const float* Wog1  = (const float*)d_in[7];
    const float* Wog2  = (const float*)d_in[8];
    const float* normw = (const float*)d_in[9];
    const float* Wo    = (const float*)d_in[10];
    float* out = (float*)d_out;

    float* ws   = (float*)d_ws;
    float* qraw = ws;
    float* kraw = ws + SZT;
    float* vraw = ws + 2 * SZT;
    float* sb   = ws + 3 * SZT;                       // 32768*656 floats
    float* ov   = sb + (size_t)32768 * RECF;
    float* f1   = ov + SZT;
    float* og1  = f1 + (size_t)4096 * 128;
    float* ybuf = qraw;

    dim3 b256(256), b128(128);

    gemm_f32<<<dim3(16, 64), b256, 0, stream>>>(x, Wq, qraw, 4096, 1024, 1024);
    gemm_f32<<<dim3(16, 64), b256, 0, stream>>>(x, Wk, kraw, 4096, 1024, 1024);
    gemm_f32<<<dim3(16, 64), b256, 0, stream>>>(x, Wv, vraw, 4096, 1024, 1024);
    gemm_f32<<<dim3(2, 64),  b256, 0, stream>>>(x, Wf1, f1,  4096, 128, 1024);
    gemm_f32<<<dim3(2, 64),  b256, 0, stream>>>(x, Wog1, og1, 4096, 128, 1024);

    prep_kernel<<<32768, b128, 0, stream>>>(x, Wbeta, Wf2, f1, qraw, kraw, vraw, sb);
    scan_kernel<<<256, b128, 0, stream>>>(sb, ov);
    post_kernel<<<32768, b128, 0, stream>>>(ov, og1, Wog2, normw, ybuf);

    gemm_f32<<<dim3(16, 64), b256, 0, stream>>>(ybuf, Wo, out, 4096, 1024, 1024);
}

// Round 3
// 1327.853 us; speedup vs baseline: 1.7437x; 1.4055x over previous
//
#include <hip/hip_runtime.h>
#include <cmath>

// DenseRnn on MI355X. Shapes: B=2, N=2048, D=1024, H=8, HD=128.
//
// Pipeline:
//  1. gemm_f32 x@Wq, x@Wk, x@Wv -> qraw/kraw/vraw [4096,1024]
//  2. gemm_f32 x@Wf1 -> f1 [4096,128]; x@Wog1 -> og1 [4096,128]
//  3. prep: per (row,h): silu, l2norm(k), beta, e=sigmoid(f); pack record
//     sb[row*8+h][656] = {k[128], e[128], ke[128], qe[128], v[128],
//                         scalars@640: beta, c=sum(e k^2), d1=sum(q e k), d2=sum(q k)}
//  4. scan: per-column recurrence, fused per-token step; all three dots taken
//     against S_prev concurrently; DPP-only 16-lane reductions; 4-deep
//     register prefetch pipeline.
//  5. post: gate = og1@Wog2, y = o*sigmoid(gate), per-head RMS, *norm_w
//  6. gemm_f32 y@Wo -> d_out

#define SZT ((size_t)4096 * 1024)
#define RECF 656           // floats per (token,b,h) record
#define RECSTRIDE 5248     // floats between consecutive tokens of same (b,h): 8*RECF

__device__ __forceinline__ float sigmf(float x) { return 1.f / (1.f + expf(-x)); }
__device__ __forceinline__ float siluf(float x) { return x * sigmf(x); }

// ---------------- fp32 GEMM: C[M,N] = A[M,K] @ B[K,N], row-major.
__global__ __launch_bounds__(256) void gemm_f32(
    const float* __restrict__ A, const float* __restrict__ B, float* __restrict__ C,
    int M, int N, int K)
{
    __shared__ float As[16][64];
    __shared__ float Bs[16][64];
    const int tid = threadIdx.x;
    const int row0 = blockIdx.y * 64;
    const int col0 = blockIdx.x * 64;
    const int tx = tid & 15, ty = tid >> 4;
    const int am = tid >> 2, akc = tid & 3;
    const int bkr = tid >> 4, bnc = tid & 15;

    float acc[4][4];
#pragma unroll
    for (int i = 0; i < 4; i++)
#pragma unroll
        for (int j = 0; j < 4; j++) acc[i][j] = 0.f;

    for (int k0 = 0; k0 < K; k0 += 16) {
        float4 av = *(const float4*)&A[(size_t)(row0 + am) * K + k0 + akc * 4];
        float4 bv = *(const float4*)&B[(size_t)(k0 + bkr) * N + col0 + bnc * 4];
        As[akc * 4 + 0][am] = av.x;
        As[akc * 4 + 1][am] = av.y;
        As[akc * 4 + 2][am] = av.z;
        As[akc * 4 + 3][am] = av.w;
        *(float4*)&Bs[bkr][bnc * 4] = bv;
        __syncthreads();
#pragma unroll
        for (int kk = 0; kk < 16; kk++) {
            float4 a = *(const float4*)&As[kk][ty * 4];
            float4 b = *(const float4*)&Bs[kk][tx * 4];
            acc[0][0] += a.x * b.x; acc[0][1] += a.x * b.y; acc[0][2] += a.x * b.z; acc[0][3] += a.x * b.w;
            acc[1][0] += a.y * b.x; acc[1][1] += a.y * b.y; acc[1][2] += a.y * b.z; acc[1][3] += a.y * b.w;
            acc[2][0] += a.z * b.x; acc[2][1] += a.z * b.y; acc[2][2] += a.z * b.z; acc[2][3] += a.z * b.w;
            acc[3][0] += a.w * b.x; acc[3][1] += a.w * b.y; acc[3][2] += a.w * b.z; acc[3][3] += a.w * b.w;
        }
        __syncthreads();
    }
#pragma unroll
    for (int i = 0; i < 4; i++) {
        float4 o = make_float4(acc[i][0], acc[i][1], acc[i][2], acc[i][3]);
        *(float4*)&C[(size_t)(row0 + ty * 4 + i) * N + col0 + tx * 4] = o;
    }
}

// ---------------- prep: one block per (row, h), 128 threads.
__global__ __launch_bounds__(128) void prep_kernel(
    const float* __restrict__ x, const float* __restrict__ Wbeta,
    const float* __restrict__ Wf2, const float* __restrict__ f1,
    const float* __restrict__ qraw, const float* __restrict__ kraw,
    const float* __restrict__ vraw, float* __restrict__ sb)
{
    const int gid = blockIdx.x;      // row*8 + h
    const int h = gid & 7;
    const int row = gid >> 3;
    const int tid = threadIdx.x;
    const int col = h * 128 + tid;
    const size_t rbase = (size_t)row * 1024;

    __shared__ float f1s[128];
    __shared__ float red[3][128];

    f1s[tid] = f1[(size_t)row * 128 + tid];

    float bsum = 0.f;
#pragma unroll
    for (int i = 0; i < 8; i++)
        bsum += x[rbase + tid + i * 128] * Wbeta[(size_t)(tid + i * 128) * 8 + h];

    float kr = kraw[rbase + col];
    float ksil = siluf(kr);

    red[0][tid] = bsum;
    red[1][tid] = ksil * ksil;
    __syncthreads();

    float fsum = 0.f;
#pragma unroll 8
    for (int i = 0; i < 128; i++) fsum += f1s[i] * Wf2[(size_t)i * 1024 + col];

    for (int off = 64; off > 0; off >>= 1) {
        if (tid < off) {
            red[0][tid] += red[0][tid + off];
            red[1][tid] += red[1][tid + off];
        }
        __syncthreads();
    }
    const float beta = 2.f * sigmf(red[0][0]);
    const float rn = rsqrtf(red[1][0] + 1e-6f);
    __syncthreads();   // all reads of red[*][0] done before reuse

    const float kn = ksil * rn;
    const float e  = sigmf(fsum);
    const float qs = siluf(qraw[rbase + col]);
    const float vs = siluf(vraw[rbase + col]);
    const float kev = e * kn;
    const float qev = e * qs;

    red[0][tid] = kev * kn;   // -> c  = sum(e k^2)
    red[1][tid] = qs * kev;   // -> d1 = sum(q e k)
    red[2][tid] = qs * kn;    // -> d2 = sum(q k)
    __syncthreads();
    for (int off = 64; off > 0; off >>= 1) {
        if (tid < off) {
            red[0][tid] += red[0][tid + off];
            red[1][tid] += red[1][tid + off];
            red[2][tid] += red[2][tid + off];
        }
        __syncthreads();
    }

    float* o = sb + (size_t)gid * RECF;
    o[tid]        = kn;
    o[128 + tid]  = e;
    o[256 + tid]  = kev;
    o[384 + tid]  = qev;
    o[512 + tid]  = vs;
    if (tid == 0) {
        o[640] = beta;
        o[641] = red[0][0];
        o[642] = red[1][0];
        o[643] = red[2][0];
    }
}

// ---------------- scan
struct TokRegs {
    float4 k0, k1, e0, e1, ke0, ke1, qe0, qe1, sc;
    float vc;
};

__device__ __forceinline__ void load_tok(const float* __restrict__ vb, int ro, int col, TokRegs& T)
{
    const float4* p4 = (const float4*)vb;
    T.k0 = p4[ro];       T.k1 = p4[ro + 1];
    T.e0 = p4[32 + ro];  T.e1 = p4[33 + ro];
    T.ke0 = p4[64 + ro]; T.ke1 = p4[65 + ro];
    T.qe0 = p4[96 + ro]; T.qe1 = p4[97 + ro];
    T.sc = p4[160];
    T.vc = vb[512 + col];
}

// 16-lane sum reduction, pure DPP (VALU pipe, no LDS).
// quad xor1, quad xor2, then half-mirror (merges octet halves), row-mirror
// (merges octets). After quad sums, any pairing permutation suffices.
__device__ __forceinline__ float red16(float x)
{
    x += __int_as_float(__builtin_amdgcn_mov_dpp(__float_as_int(x), 0xB1,  0xF, 0xF, true)); // quad_perm [1,0,3,2]
    x += __int_as_float(__builtin_amdgcn_mov_dpp(__float_as_int(x), 0x4E,  0xF, 0xF, true)); // quad_perm [2,3,0,1]
    x += __int_as_float(__builtin_amdgcn_mov_dpp(__float_as_int(x), 0x141, 0xF, 0xF, true)); // row_half_mirror
    x += __int_as_float(__builtin_amdgcn_mov_dpp(__float_as_int(x), 0x140, 0xF, 0xF, true)); // row_mirror
    return x;
}

#define SCAN_STEP(T, OUTIDX)                                                          \
  {                                                                                   \
    float bS  = ((T.k0.x * S0 + T.k0.y * S1) + (T.k0.z * S2 + T.k0.w * S3))           \
              + ((T.k1.x * S4 + T.k1.y * S5) + (T.k1.z * S6 + T.k1.w * S7));          \
    float keS = ((T.ke0.x * S0 + T.ke0.y * S1) + (T.ke0.z * S2 + T.ke0.w * S3))       \
              + ((T.ke1.x * S4 + T.ke1.y * S5) + (T.ke1.z * S6 + T.ke1.w * S7));      \
    float qeS = ((T.qe0.x * S0 + T.qe0.y * S1) + (T.qe0.z * S2 + T.qe0.w * S3))       \
              + ((T.qe1.x * S4 + T.qe1.y * S5) + (T.qe1.z * S6 + T.qe1.w * S7));      \
    bS = red16(bS); keS = red16(keS); qeS = red16(qeS);                               \
    const float bSb = T.sc.x * bS;                                                    \
    const float ks  = keS - bSb * T.sc.y;                                             \
    const float w   = T.vc - T.sc.x * ks;                                             \
    const float o   = (qeS - bSb * T.sc.z) + w * T.sc.w;                              \
    S0 = (T.e0.x * S0 - bSb * T.ke0.x) + w * T.k0.x;                                  \
    S1 = (T.e0.y * S1 - bSb * T.ke0.y) + w * T.k0.y;                                  \
    S2 = (T.e0.z * S2 - bSb * T.ke0.z) + w * T.k0.z;                                  \
    S3 = (T.e0.w * S3 - bSb * T.ke0.w) + w * T.k0.w;                                  \
    S4 = (T.e1.x * S4 - bSb * T.ke1.x) + w * T.k1.x;                                  \
    S5 = (T.e1.y * S5 - bSb * T.ke1.y) + w * T.k1.y;                                  \
    S6 = (T.e1.z * S6 - bSb * T.ke1.z) + w * T.k1.z;                                  \
    S7 = (T.e1.w * S7 - bSb * T.ke1.w) + w * T.k1.w;                                  \
    if (rg == 0) ov[OUTIDX] = o;                                                      \
  }

__device__ __forceinline__ const float* recp(const float* p0, int t)
{
    const int tc = (t < 2048) ? t : 2047;   // tail clamp; clamped loads are unused
    return p0 + (size_t)tc * RECSTRIDE;
}

// 256 blocks x 128 threads. block -> (bh = blk>>4, cg = blk&15); 8 cols/block,
// 16 lanes/col, each lane owns 8 state rows. 4-deep register prefetch.
__global__ __launch_bounds__(128) void scan_kernel(
    const float* __restrict__ sb, float* __restrict__ ov)
{
    const int tid = threadIdx.x;
    const int blk = blockIdx.x;
    const int bh = blk >> 4;
    const int cg = blk & 15;
    const int b = bh >> 3, h = bh & 7;
    const int col = cg * 8 + (tid >> 4);
    const int rg = tid & 15;
    const int ro = rg * 2;

    float S0 = 0.f, S1 = 0.f, S2 = 0.f, S3 = 0.f, S4 = 0.f, S5 = 0.f, S6 = 0.f, S7 = 0.f;

    const size_t base = (size_t)b * 2048 * 8 + h;
    const float* p0 = sb + base * RECF;
    size_t oidx = base * 128 + col;

    TokRegs A, B, C, D;
    load_tok(recp(p0, 0), ro, col, A);
    load_tok(recp(p0, 1), ro, col, B);
    load_tok(recp(p0, 2), ro, col, C);
    load_tok(recp(p0, 3), ro, col, D);

    for (int t = 0; t < 2048; t += 4) {
        SCAN_STEP(A, oidx);
        load_tok(recp(p0, t + 4), ro, col, A);
        SCAN_STEP(B, oidx + 1024);
        load_tok(recp(p0, t + 5), ro, col, B);
        SCAN_STEP(C, oidx + 2048);
        load_tok(recp(p0, t + 6), ro, col, C);
        SCAN_STEP(D, oidx + 3072);
        load_tok(recp(p0, t + 7), ro, col, D);
        oidx += 4096;
    }
}

// ---------------- post
__global__ __launch_bounds__(128) void post_kernel(
    const float* __restrict__ ov, const float* __restrict__ og1,
    const float* __restrict__ Wog2, const float* __restrict__ normw,
    float* __restrict__ ybuf)
{
    const int gid = blockIdx.x;
    const int h = gid & 7;
    const int row = gid >> 3;
    const int tid = threadIdx.x;
    const int col = h * 128 + tid;

    __shared__ float ogs[128];
    __shared__ float red[128];

    ogs[tid] = og1[(size_t)row * 128 + tid];
    __syncthreads();

    float g = 0.f;
#pragma unroll 8
    for (int i = 0; i < 128; i++) g += ogs[i] * Wog2[(size_t)i * 1024 + col];

    const float o = ov[(size_t)row * 1024 + col];
    const float y = o * sigmf(g);

    red[tid] = y * y;
    __syncthreads();
    for (int off = 64; off > 0; off >>= 1) {
        if (tid < off) red[tid] += red[tid + off];
        __syncthreads();
    }
    const float rms = rsqrtf(red[0] * (1.f / 128.f) + 1e-6f);
    ybuf[(size_t)row * 1024 + col] = y * rms * normw[col];
}

extern "C" void kernel_launch(void* const* d_in, const int* in_sizes, int n_in,
                              void* d_out, int out_size, void* d_ws, size_t ws_size,
                              hipStream_t stream)
{
    const float* x     = (const float*)d_in[0];
    const float* Wq    = (const float*)d_in[1];
    const float* Wk    = (const float*)d_in[2];
    const float* Wv    = (const float*)d_in[3];
    const float* Wf1   = (const float*)d_in[4];
    const float* Wf2   = (const float*)d_in[5];
    const float* Wbeta = (const float*)d_in[6];
    const float* Wog1  = (const float*)d_in[7];
    const float* Wog2  = (const float*)d_in[8];
    const float* normw = (const float*)d_in[9];
    const float* Wo    = (const float*)d_in[10];
    float* out = (float*)d_out;

    float* ws   = (float*)d_ws;
    float* qraw = ws;
    float* kraw = ws + SZT;
    float* vraw = ws + 2 * SZT;
    float* sb   = ws + 3 * SZT;                       // 32768*656 floats
    float* ov   = sb + (size_t)32768 * RECF;
    float* f1   = ov + SZT;
    float* og1  = f1 + (size_t)4096 * 128;
    float* ybuf = qraw;

    dim3 b256(256), b128(128);

    gemm_f32<<<dim3(16, 64), b256, 0, stream>>>(x, Wq, qraw, 4096, 1024, 1024);
    gemm_f32<<<dim3(16, 64), b256, 0, stream>>>(x, Wk, kraw, 4096, 1024, 1024);
    gemm_f32<<<dim3(16, 64), b256, 0, stream>>>(x, Wv, vraw, 4096, 1024, 1024);
    gemm_f32<<<dim3(2, 64),  b256, 0, stream>>>(x, Wf1, f1,  4096, 128, 1024);
    gemm_f32<<<dim3(2, 64),  b256, 0, stream>>>(x, Wog1, og1, 4096, 128, 1024);

    prep_kernel<<<32768, b128, 0, stream>>>(x, Wbeta, Wf2, f1, qraw, kraw, vraw, sb);
    scan_kernel<<<256, b128, 0, stream>>>(sb, ov);
    post_kernel<<<32768, b128, 0, stream>>>(ov, og1, Wog2, normw, ybuf);

    gemm_f32<<<dim3(16, 64), b256, 0, stream>>>(ybuf, Wo, out, 4096, 1024, 1024);
}

// Round 5
// 1303.179 us; speedup vs baseline: 1.7767x; 1.0189x over previous
//
#include <hip/hip_runtime.h>
#include <cmath>

// DenseRnn on MI355X. Shapes: B=2, N=2048, D=1024, H=8, HD=128.
//
//  1. wtrans_split: Wq/Wk/Wv fp32 [K][N] -> bf16 hi+lo WT [N][K]; Wo -> plain bf16 WT
//     conv_split: x -> bf16 hi+lo
//  2. gemm_bf16_split (MFMA 16x16x32, 3-term bf16x2): qraw/kraw/vraw = x@W, ~fp32 accuracy
//  3. gemm_f32 x@Wf1 -> f1; x@Wog1 -> og1 (low-rank, fp32)
//  4. prep: silu/l2norm/beta/e, pack per-(row,h) record + fused scalars
//  5. scan: per-column recurrence, 32 lanes/col x 4 rows/lane, DPP+swizzle
//     reductions, 4-deep register prefetch; 1024 waves = 1/SIMD chip-wide.
//  6. post: gate, sigmoid, per-head RMS, *norm_w -> bf16 y
//  7. gemm_bf16 y@Wo -> out (plain bf16: no recurrence amplification here)

#define SZT ((size_t)4096 * 1024)
#define RECF 656
#define RECSTRIDE 5248     // 8*RECF

typedef unsigned short u16;
typedef __attribute__((ext_vector_type(8))) short short8;
typedef __attribute__((ext_vector_type(4))) float f32x4;

__device__ __forceinline__ float sigmf(float x) { return 1.f / (1.f + expf(-x)); }
__device__ __forceinline__ float siluf(float x) { return x * sigmf(x); }
__device__ __forceinline__ u16 f2bf(float f) {
    unsigned int u = __float_as_uint(f);
    unsigned int r = (u + 0x7FFFu + ((u >> 16) & 1u)) >> 16;
    return (u16)r;
}
__device__ __forceinline__ float bf2f(u16 h) { return __uint_as_float((unsigned int)h << 16); }
__device__ __forceinline__ void splitbf(float f, u16& hi, u16& lo) {
    hi = f2bf(f);
    lo = f2bf(f - bf2f(hi));
}

#define GLOAD_LDS16(gp, lp) __builtin_amdgcn_global_load_lds( \
    (const __attribute__((address_space(1))) void*)(gp),      \
    (__attribute__((address_space(3))) void*)(lp), 16, 0, 0)

// ---------------- transpose+convert (split): W fp32 [1024][1024] -> hi/lo bf16 [N][K]
__global__ __launch_bounds__(256) void wtrans_split(
    const float* __restrict__ W, u16* __restrict__ WTh, u16* __restrict__ WTl)
{
    __shared__ float t[32][33];
    const int tx = threadIdx.x & 31, ty = threadIdx.x >> 5;
    const int n0 = blockIdx.x * 32, k0 = blockIdx.y * 32;
#pragma unroll
    for (int i = 0; i < 4; i++)
        t[ty + i * 8][tx] = W[(size_t)(k0 + ty + i * 8) * 1024 + n0 + tx];
    __syncthreads();
#pragma unroll
    for (int i = 0; i < 4; i++) {
        u16 hi, lo;
        splitbf(t[tx][ty + i * 8], hi, lo);
        WTh[(size_t)(n0 + ty + i * 8) * 1024 + k0 + tx] = hi;
        WTl[(size_t)(n0 + ty + i * 8) * 1024 + k0 + tx] = lo;
    }
}

// ---------------- transpose+convert (plain)
__global__ __launch_bounds__(256) void wtrans(const float* __restrict__ W, u16* __restrict__ WT)
{
    __shared__ float t[32][33];
    const int tx = threadIdx.x & 31, ty = threadIdx.x >> 5;
    const int n0 = blockIdx.x * 32, k0 = blockIdx.y * 32;
#pragma unroll
    for (int i = 0; i < 4; i++)
        t[ty + i * 8][tx] = W[(size_t)(k0 + ty + i * 8) * 1024 + n0 + tx];
    __syncthreads();
#pragma unroll
    for (int i = 0; i < 4; i++)
        WT[(size_t)(n0 + ty + i * 8) * 1024 + k0 + tx] = f2bf(t[tx][ty + i * 8]);
}

// ---------------- fp32 -> bf16 hi/lo elementwise
__global__ __launch_bounds__(256) void conv_split(
    const float* __restrict__ in, u16* __restrict__ oh, u16* __restrict__ ol)
{
    const size_t i = ((size_t)blockIdx.x * 256 + threadIdx.x) * 8;
    short8 rh, rl;
#pragma unroll
    for (int j = 0; j < 8; j++) {
        u16 hi, lo;
        splitbf(in[i + j], hi, lo);
        rh[j] = (short)hi; rl[j] = (short)lo;
    }
    *(short8*)&oh[i] = rh;
    *(short8*)&ol[i] = rl;
}

// ---------------- split bf16 MFMA GEMM: C = (Ah+Al) @ (BTh+BTl)^T (3-term), fp32 out.
// 128x128 tile, BK=32, 256 threads (4 waves 2x2).
__global__ __launch_bounds__(256) void gemm_bf16_split(
    const u16* __restrict__ Ah, const u16* __restrict__ Al,
    const u16* __restrict__ BTh, const u16* __restrict__ BTl,
    float* __restrict__ C, int M, int N, int K)
{
    __shared__ u16 AsH[128 * 32];
    __shared__ u16 AsL[128 * 32];
    __shared__ u16 BsH[128 * 32];
    __shared__ u16 BsL[128 * 32];
    const int tid = threadIdx.x;
    const int lane = tid & 63;
    const int w = tid >> 6;
    const int wr = w >> 1, wc = w & 1;
    const int row0 = blockIdx.y * 128;
    const int col0 = blockIdx.x * 128;
    const int mrow = lane & 15;
    const int kgrp = (lane >> 4) * 8;

    f32x4 acc[4][4] = {};

    const int off0 = w * 1024 + lane * 16;
    const int r0 = off0 >> 6, kl0 = (off0 & 63) >> 1;
    const int off1 = off0 + 4096;
    const int r1 = off1 >> 6, kl1 = (off1 & 63) >> 1;

    for (int kt = 0; kt < K; kt += 32) {
        GLOAD_LDS16(Ah  + (size_t)(row0 + r0) * K + kt + kl0, (char*)AsH + w * 1024);
        GLOAD_LDS16(Ah  + (size_t)(row0 + r1) * K + kt + kl1, (char*)AsH + w * 1024 + 4096);
        GLOAD_LDS16(Al  + (size_t)(row0 + r0) * K + kt + kl0, (char*)AsL + w * 1024);
        GLOAD_LDS16(Al  + (size_t)(row0 + r1) * K + kt + kl1, (char*)AsL + w * 1024 + 4096);
        GLOAD_LDS16(BTh + (size_t)(col0 + r0) * K + kt + kl0, (char*)BsH + w * 1024);
        GLOAD_LDS16(BTh + (size_t)(col0 + r1) * K + kt + kl1, (char*)BsH + w * 1024 + 4096);
        GLOAD_LDS16(BTl + (size_t)(col0 + r0) * K + kt + kl0, (char*)BsL + w * 1024);
        GLOAD_LDS16(BTl + (size_t)(col0 + r1) * K + kt + kl1, (char*)BsL + w * 1024 + 4096);
        __syncthreads();

        short8 aH[4], aL[4], bH[4], bL[4];
#pragma unroll
        for (int mi = 0; mi < 4; ++mi) {
            aH[mi] = *(const short8*)&AsH[(wr * 64 + mi * 16 + mrow) * 32 + kgrp];
            aL[mi] = *(const short8*)&AsL[(wr * 64 + mi * 16 + mrow) * 32 + kgrp];
        }
#pragma unroll
        for (int ni = 0; ni < 4; ++ni) {
            bH[ni] = *(const short8*)&BsH[(wc * 64 + ni * 16 + mrow) * 32 + kgrp];
            bL[ni] = *(const short8*)&BsL[(wc * 64 + ni * 16 + mrow) * 32 + kgrp];
        }
#pragma unroll
        for (int mi = 0; mi < 4; ++mi)
#pragma unroll
            for (int ni = 0; ni < 4; ++ni) {
                acc[mi][ni] = __builtin_amdgcn_mfma_f32_16x16x32_bf16(aH[mi], bH[ni], acc[mi][ni], 0, 0, 0);
                acc[mi][ni] = __builtin_amdgcn_mfma_f32_16x16x32_bf16(aL[mi], bH[ni], acc[mi][ni], 0, 0, 0);
                acc[mi][ni] = __builtin_amdgcn_mfma_f32_16x16x32_bf16(aH[mi], bL[ni], acc[mi][ni], 0, 0, 0);
            }
        __syncthreads();
    }

    const int crow = (lane >> 4) * 4;
#pragma unroll
    for (int mi = 0; mi < 4; ++mi)
#pragma unroll
        for (int ni = 0; ni < 4; ++ni)
#pragma unroll
            for (int j = 0; j < 4; ++j)
                C[(size_t)(row0 + wr * 64 + mi * 16 + crow + j) * N + col0 + wc * 64 + ni * 16 + mrow]
                    = acc[mi][ni][j];
}

// ---------------- plain bf16 MFMA GEMM (final projection)
__global__ __launch_bounds__(256) void gemm_bf16(
    const u16* __restrict__ A, const u16* __restrict__ BT, float* __restrict__ C,
    int M, int N, int K)
{
    __shared__ u16 As[128 * 32];
    __shared__ u16 Bs[128 * 32];
    const int tid = threadIdx.x;
    const int lane = tid & 63;
    const int w = tid >> 6;
    const int wr = w >> 1, wc = w & 1;
    const int row0 = blockIdx.y * 128;
    const int col0 = blockIdx.x * 128;
    const int mrow = lane & 15;
    const int kgrp = (lane >> 4) * 8;

    f32x4 acc[4][4] = {};

    const int off0 = w * 1024 + lane * 16;
    const int r0 = off0 >> 6, kl0 = (off0 & 63) >> 1;
    const int off1 = off0 + 4096;
    const int r1 = off1 >> 6, kl1 = (off1 & 63) >> 1;

    for (int kt = 0; kt < K; kt += 32) {
        GLOAD_LDS16(A  + (size_t)(row0 + r0) * K + kt + kl0, (char*)As + w * 1024);
        GLOAD_LDS16(A  + (size_t)(row0 + r1) * K + kt + kl1, (char*)As + w * 1024 + 4096);
        GLOAD_LDS16(BT + (size_t)(col0 + r0) * K + kt + kl0, (char*)Bs + w * 1024);
        GLOAD_LDS16(BT + (size_t)(col0 + r1) * K + kt + kl1, (char*)Bs + w * 1024 + 4096);
        __syncthreads();

        short8 aF[4], bF[4];
#pragma unroll
        for (int mi = 0; mi < 4; ++mi)
            aF[mi] = *(const short8*)&As[(wr * 64 + mi * 16 + mrow) * 32 + kgrp];
#pragma unroll
        for (int ni = 0; ni < 4; ++ni)
            bF[ni] = *(const short8*)&Bs[(wc * 64 + ni * 16 + mrow) * 32 + kgrp];
#pragma unroll
        for (int mi = 0; mi < 4; ++mi)
#pragma unroll
            for (int ni = 0; ni < 4; ++ni)
                acc[mi][ni] = __builtin_amdgcn_mfma_f32_16x16x32_bf16(aF[mi], bF[ni], acc[mi][ni], 0, 0, 0);
        __syncthreads();
    }

    const int crow = (lane >> 4) * 4;
#pragma unroll
    for (int mi = 0; mi < 4; ++mi)
#pragma unroll
        for (int ni = 0; ni < 4; ++ni)
#pragma unroll
            for (int j = 0; j < 4; ++j)
                C[(size_t)(row0 + wr * 64 + mi * 16 + crow + j) * N + col0 + wc * 64 + ni * 16 + mrow]
                    = acc[mi][ni][j];
}

// ---------------- fp32 GEMM (low-rank paths)
__global__ __launch_bounds__(256) void gemm_f32(
    const float* __restrict__ A, const float* __restrict__ B, float* __restrict__ C,
    int M, int N, int K)
{
    __shared__ float As[16][64];
    __shared__ float Bs[16][64];
    const int tid = threadIdx.x;
    const int row0 = blockIdx.y * 64;
    const int col0 = blockIdx.x * 64;
    const int tx = tid & 15, ty = tid >> 4;
    const int am = tid >> 2, akc = tid & 3;
    const int bkr = tid >> 4, bnc = tid & 15;

    float acc[4][4];
#pragma unroll
    for (int i = 0; i < 4; i++)
#pragma unroll
        for (int j = 0; j < 4; j++) acc[i][j] = 0.f;

    for (int k0 = 0; k0 < K; k0 += 16) {
        float4 av = *(const float4*)&A[(size_t)(row0 + am) * K + k0 + akc * 4];
        float4 bv = *(const float4*)&B[(size_t)(k0 + bkr) * N + col0 + bnc * 4];
        As[akc * 4 + 0][am] = av.x;
        As[akc * 4 + 1][am] = av.y;
        As[akc * 4 + 2][am] = av.z;
        As[akc * 4 + 3][am] = av.w;
        *(float4*)&Bs[bkr][bnc * 4] = bv;
        __syncthreads();
#pragma unroll
        for (int kk = 0; kk < 16; kk++) {
            float4 a = *(const float4*)&As[kk][ty * 4];
            float4 b = *(const float4*)&Bs[kk][tx * 4];
            acc[0][0] += a.x * b.x; acc[0][1] += a.x * b.y; acc[0][2] += a.x * b.z; acc[0][3] += a.x * b.w;
            acc[1][0] += a.y * b.x; acc[1][1] += a.y * b.y; acc[1][2] += a.y * b.z; acc[1][3] += a.y * b.w;
            acc[2][0] += a.z * b.x; acc[2][1] += a.z * b.y; acc[2][2] += a.z * b.z; acc[2][3] += a.z * b.w;
            acc[3][0] += a.w * b.x; acc[3][1] += a.w * b.y; acc[3][2] += a.w * b.z; acc[3][3] += a.w * b.w;
        }
        __syncthreads();
    }
#pragma unroll
    for (int i = 0; i < 4; i++) {
        float4 o = make_float4(acc[i][0], acc[i][1], acc[i][2], acc[i][3]);
        *(float4*)&C[(size_t)(row0 + ty * 4 + i) * N + col0 + tx * 4] = o;
    }
}

// ---------------- prep: one block per (row, h), 128 threads.
__global__ __launch_bounds__(128) void prep_kernel(
    const float* __restrict__ x, const float* __restrict__ Wbeta,
    const float* __restrict__ Wf2, const float* __restrict__ f1,
    const float* __restrict__ qraw, const float* __restrict__ kraw,
    const float* __restrict__ vraw, float* __restrict__ sb)
{
    const int gid = blockIdx.x;
    const int h = gid & 7;
    const int row = gid >> 3;
    const int tid = threadIdx.x;
    const int col = h * 128 + tid;
    const size_t rbase = (size_t)row * 1024;

    __shared__ float f1s[128];
    __shared__ float red[3][128];

    f1s[tid] = f1[(size_t)row * 128 + tid];

    float bsum = 0.f;
#pragma unroll
    for (int i = 0; i < 8; i++)
        bsum += x[rbase + tid + i * 128] * Wbeta[(size_t)(tid + i * 128) * 8 + h];

    float kr = kraw[rbase + col];
    float ksil = siluf(kr);

    red[0][tid] = bsum;
    red[1][tid] = ksil * ksil;
    __syncthreads();

    float fsum = 0.f;
#pragma unroll 8
    for (int i = 0; i < 128; i++) fsum += f1s[i] * Wf2[(size_t)i * 1024 + col];

    for (int off = 64; off > 0; off >>= 1) {
        if (tid < off) {
            red[0][tid] += red[0][tid + off];
            red[1][tid] += red[1][tid + off];
        }
        __syncthreads();
    }
    const float beta = 2.f * sigmf(red[0][0]);
    const float rn = rsqrtf(red[1][0] + 1e-6f);
    __syncthreads();

    const float kn = ksil * rn;
    const float e  = sigmf(fsum);
    const float qs = siluf(qraw[rbase + col]);
    const float vs = siluf(vraw[rbase + col]);
    const float kev = e * kn;
    const float qev = e * qs;

    red[0][tid] = kev * kn;
    red[1][tid] = qs * kev;
    red[2][tid] = qs * kn;
    __syncthreads();
    for (int off = 64; off > 0; off >>= 1) {
        if (tid < off) {
            red[0][tid] += red[0][tid + off];
            red[1][tid] += red[1][tid + off];
            red[2][tid] += red[2][tid + off];
        }
        __syncthreads();
    }

    float* o = sb + (size_t)gid * RECF;
    o[tid]        = kn;
    o[128 + tid]  = e;
    o[256 + tid]  = kev;
    o[384 + tid]  = qev;
    o[512 + tid]  = vs;
    if (tid == 0) {
        o[640] = beta;
        o[641] = red[0][0];
        o[642] = red[1][0];
        o[643] = red[2][0];
    }
}

// ---------------- scan
struct TokR { float4 k, e, ke, qe, sc; float vc; };

__device__ __forceinline__ void load_tok4(const float* __restrict__ vb, int rg, int col, TokR& T)
{
    const float4* p4 = (const float4*)vb;
    T.k = p4[rg]; T.e = p4[32 + rg]; T.ke = p4[64 + rg]; T.qe = p4[96 + rg];
    T.sc = p4[160];
    T.vc = vb[512 + col];
}

// 32-lane sum: 4 DPP stages (within 16) + ds_swizzle xor16 (within 32).
__device__ __forceinline__ float red32(float x)
{
    x += __int_as_float(__builtin_amdgcn_mov_dpp(__float_as_int(x), 0xB1,  0xF, 0xF, true));
    x += __int_as_float(__builtin_amdgcn_mov_dpp(__float_as_int(x), 0x4E,  0xF, 0xF, true));
    x += __int_as_float(__builtin_amdgcn_mov_dpp(__float_as_int(x), 0x141, 0xF, 0xF, true));
    x += __int_as_float(__builtin_amdgcn_mov_dpp(__float_as_int(x), 0x140, 0xF, 0xF, true));
    x += __int_as_float(__builtin_amdgcn_ds_swizzle(__float_as_int(x), 0x401F));
    return x;
}

#define SCAN_STEP4(T, OUTIDX)                                                   \
  {                                                                             \
    float bS  = (T.k.x  * S0 + T.k.y  * S1) + (T.k.z  * S2 + T.k.w  * S3);      \
    float keS = (T.ke.x * S0 + T.ke.y * S1) + (T.ke.z * S2 + T.ke.w * S3);      \
    float qeS = (T.qe.x * S0 + T.qe.y * S1) + (T.qe.z * S2 + T.qe.w * S3);      \
    bS = red32(bS); keS = red32(keS); qeS = red32(qeS);                         \
    const float bSb = T.sc.x * bS;                                              \
    const float ks  = keS - bSb * T.sc.y;                                       \
    const float w   = T.vc - T.sc.x * ks;                                       \
    const float o   = (qeS - bSb * T.sc.z) + w * T.sc.w;                        \
    S0 = (T.e.x * S0 - bSb * T.ke.x) + w * T.k.x;                               \
    S1 = (T.e.y * S1 - bSb * T.ke.y) + w * T.k.y;                               \
    S2 = (T.e.z * S2 - bSb * T.ke.z) + w * T.k.z;                               \
    S3 = (T.e.w * S3 - bSb * T.ke.w) + w * T.k.w;                               \
    if (rg == 0) ov[OUTIDX] = o;                                                \
  }

__device__ __forceinline__ const float* recp(const float* p0, int t)
{
    const int tc = (t < 2048) ? t : 2047;
    return p0 + (size_t)tc * RECSTRIDE;
}

// 256 blocks x 256 threads (4 waves); 8 cols/block, 32 lanes/col, 4 rows/lane.
__global__ __launch_bounds__(256) void scan_kernel(
    const float* __restrict__ sb, float* __restrict__ ov)
{
    const int tid = threadIdx.x;
    const int blk = blockIdx.x;
    const int bh = blk >> 4;
    const int cg = blk & 15;
    const int b = bh >> 3, h = bh & 7;
    const int cl = tid >> 5;
    const int rg = tid & 31;
    const int col = cg * 8 + cl;

    float S0 = 0.f, S1 = 0.f, S2 = 0.f, S3 = 0.f;

    const size_t base = (size_t)b * 2048 * 8 + h;
    const float* p0 = sb + base * RECF;
    size_t oidx = base * 128 + col;

    TokR A, B, C, D;
    load_tok4(recp(p0, 0), rg, col, A);
    load_tok4(recp(p0, 1), rg, col, B);
    load_tok4(recp(p0, 2), rg, col, C);
    load_tok4(recp(p0, 3), rg, col, D);

    for (int t = 0; t < 2048; t += 4) {
        SCAN_STEP4(A, oidx);
        load_tok4(recp(p0, t + 4), rg, col, A);
        SCAN_STEP4(B, oidx + 1024);
        load_tok4(recp(p0, t + 5), rg, col, B);
        SCAN_STEP4(C, oidx + 2048);
        load_tok4(recp(p0, t + 6), rg, col, C);
        SCAN_STEP4(D, oidx + 3072);
        load_tok4(recp(p0, t + 7), rg, col, D);
        oidx += 4096;
    }
}

// ---------------- post: writes bf16 y
__global__ __launch_bounds__(128) void post_kernel(
    const float* __restrict__ ov, const float* __restrict__ og1,
    const float* __restrict__ Wog2, const float* __restrict__ normw,
    u16* __restrict__ ybf)
{
    const int gid = blockIdx.x;
    const int h = gid & 7;
    const int row = gid >> 3;
    const int tid = threadIdx.x;
    const int col = h * 128 + tid;

    __shared__ float ogs[128];
    __shared__ float red[128];

    ogs[tid] = og1[(size_t)row * 128 + tid];
    __syncthreads();

    float g = 0.f;
#pragma unroll 8
    for (int i = 0; i < 128; i++) g += ogs[i] * Wog2[(size_t)i * 1024 + col];

    const float o = ov[(size_t)row * 1024 + col];
    const float y = o * sigmf(g);

    red[tid] = y * y;
    __syncthreads();
    for (int off = 64; off > 0; off >>= 1) {
        if (tid < off) red[tid] += red[tid + off];
        __syncthreads();
    }
    const float rms = rsqrtf(red[0] * (1.f / 128.f) + 1e-6f);
    ybf[(size_t)row * 1024 + col] = f2bf(y * rms * normw[col]);
}

extern "C" void kernel_launch(void* const* d_in, const int* in_sizes, int n_in,
                              void* d_out, int out_size, void* d_ws, size_t ws_size,
                              hipStream_t stream)
{
    const float* x     = (const float*)d_in[0];
    const float* Wq    = (const float*)d_in[1];
    const float* Wk    = (const float*)d_in[2];
    const float* Wv    = (const float*)d_in[3];
    const float* Wf1   = (const float*)d_in[4];
    const float* Wf2   = (const float*)d_in[5];
    const float* Wbeta = (const float*)d_in[6];
    const float* Wog1  = (const float*)d_in[7];
    const float* Wog2  = (const float*)d_in[8];
    const float* normw = (const float*)d_in[9];
    const float* Wo    = (const float*)d_in[10];
    float* out = (float*)d_out;

    float* ws   = (float*)d_ws;
    float* qraw = ws;                                 // 4M floats
    float* kraw = ws + SZT;
    float* vraw = ws + 2 * SZT;
    float* sb   = ws + 3 * SZT;                       // 32768*656 floats
    float* ov   = sb + (size_t)32768 * RECF;          // 4M floats; WT hi/lo live here early
    float* f1   = ov + SZT;                           // 0.5M
    float* og1  = f1 + (size_t)4096 * 128;            // 0.5M
    float* xsp  = og1 + (size_t)4096 * 128;           // 4M floats (xh, xl as u16)
    float* wot  = xsp + SZT;                          // 0.5M floats (WoT)

    u16* xh  = (u16*)xsp;                             // 4M u16
    u16* xl  = xh + SZT;                              // 4M u16
    u16* WoT = (u16*)wot;

    u16* WqTh = (u16*)ov;                             // 6 x 1M u16 inside ov
    u16* WqTl = WqTh + (size_t)1024 * 1024;
    u16* WkTh = WqTl + (size_t)1024 * 1024;
    u16* WkTl = WkTh + (size_t)1024 * 1024;
    u16* WvTh = WkTl + (size_t)1024 * 1024;
    u16* WvTl = WvTh + (size_t)1024 * 1024;

    u16* ybf = (u16*)vraw;                            // vraw dead after prep

    dim3 b256(256), b128(128);

    wtrans_split<<<dim3(32, 32), b256, 0, stream>>>(Wq, WqTh, WqTl);
    wtrans_split<<<dim3(32, 32), b256, 0, stream>>>(Wk, WkTh, WkTl);
    wtrans_split<<<dim3(32, 32), b256, 0, stream>>>(Wv, WvTh, WvTl);
    wtrans<<<dim3(32, 32), b256, 0, stream>>>(Wo, WoT);
    conv_split<<<2048, b256, 0, stream>>>(x, xh, xl);

    gemm_bf16_split<<<dim3(8, 32), b256, 0, stream>>>(xh, xl, WqTh, WqTl, qraw, 4096, 1024, 1024);
    gemm_bf16_split<<<dim3(8, 32), b256, 0, stream>>>(xh, xl, WkTh, WkTl, kraw, 4096, 1024, 1024);
    gemm_bf16_split<<<dim3(8, 32), b256, 0, stream>>>(xh, xl, WvTh, WvTl, vraw, 4096, 1024, 1024);
    gemm_f32<<<dim3(2, 64),  b256, 0, stream>>>(x, Wf1, f1,  4096, 128, 1024);
    gemm_f32<<<dim3(2, 64),  b256, 0, stream>>>(x, Wog1, og1, 4096, 128, 1024);

    prep_kernel<<<32768, b128, 0, stream>>>(x, Wbeta, Wf2, f1, qraw, kraw, vraw, sb);
    scan_kernel<<<256, b256, 0, stream>>>(sb, ov);
    post_kernel<<<32768, b128, 0, stream>>>(ov, og1, Wog2, normw, ybf);

    gemm_bf16<<<dim3(8, 32), b256, 0, stream>>>(ybf, WoT, out, 4096, 1024, 1024);
}

// Round 6
// 1216.622 us; speedup vs baseline: 1.9031x; 1.0711x over previous
//
#include <hip/hip_runtime.h>
#include <cmath>

// DenseRnn on MI355X. Shapes: B=2, N=2048, D=1024, H=8, HD=128.
//
//  1. wtrans_split: Wq/Wk/Wv fp32 [K][N] -> bf16 hi+lo WT [N][K]; Wo -> plain bf16 WT
//     conv_split: x -> bf16 hi+lo
//  2. gemm_bf16_split (MFMA 16x16x32, 3-term bf16x2): qraw/kraw/vraw = x@W, ~fp32 accuracy
//  3. gemm_f32 x@Wf1 -> f1; x@Wog1 -> og1 (low-rank, fp32)
//  4. prep: silu/l2norm/beta/e, pack per-(row,h) record + fused scalars
//  5. scan: per-column recurrence, 32 lanes/col x 4 rows/lane, DPP+swizzle
//     reductions, 8-deep register prefetch pinned with sched_barrier(0).
//  6. post: gate, sigmoid, per-head RMS, *norm_w -> bf16 y
//  7. gemm_bf16 y@Wo -> out (plain bf16: no recurrence amplification here)

#define SZT ((size_t)4096 * 1024)
#define RECF 656
#define RECSTRIDE 5248     // 8*RECF

typedef unsigned short u16;
typedef __attribute__((ext_vector_type(8))) short short8;
typedef __attribute__((ext_vector_type(4))) float f32x4;

__device__ __forceinline__ float sigmf(float x) { return 1.f / (1.f + expf(-x)); }
__device__ __forceinline__ float siluf(float x) { return x * sigmf(x); }
__device__ __forceinline__ u16 f2bf(float f) {
    unsigned int u = __float_as_uint(f);
    unsigned int r = (u + 0x7FFFu + ((u >> 16) & 1u)) >> 16;
    return (u16)r;
}
__device__ __forceinline__ float bf2f(u16 h) { return __uint_as_float((unsigned int)h << 16); }
__device__ __forceinline__ void splitbf(float f, u16& hi, u16& lo) {
    hi = f2bf(f);
    lo = f2bf(f - bf2f(hi));
}

#define GLOAD_LDS16(gp, lp) __builtin_amdgcn_global_load_lds( \
    (const __attribute__((address_space(1))) void*)(gp),      \
    (__attribute__((address_space(3))) void*)(lp), 16, 0, 0)

// ---------------- transpose+convert (split): W fp32 [1024][1024] -> hi/lo bf16 [N][K]
__global__ __launch_bounds__(256) void wtrans_split(
    const float* __restrict__ W, u16* __restrict__ WTh, u16* __restrict__ WTl)
{
    __shared__ float t[32][33];
    const int tx = threadIdx.x & 31, ty = threadIdx.x >> 5;
    const int n0 = blockIdx.x * 32, k0 = blockIdx.y * 32;
#pragma unroll
    for (int i = 0; i < 4; i++)
        t[ty + i * 8][tx] = W[(size_t)(k0 + ty + i * 8) * 1024 + n0 + tx];
    __syncthreads();
#pragma unroll
    for (int i = 0; i < 4; i++) {
        u16 hi, lo;
        splitbf(t[tx][ty + i * 8], hi, lo);
        WTh[(size_t)(n0 + ty + i * 8) * 1024 + k0 + tx] = hi;
        WTl[(size_t)(n0 + ty + i * 8) * 1024 + k0 + tx] = lo;
    }
}

// ---------------- transpose+convert (plain)
__global__ __launch_bounds__(256) void wtrans(const float* __restrict__ W, u16* __restrict__ WT)
{
    __shared__ float t[32][33];
    const int tx = threadIdx.x & 31, ty = threadIdx.x >> 5;
    const int n0 = blockIdx.x * 32, k0 = blockIdx.y * 32;
#pragma unroll
    for (int i = 0; i < 4; i++)
        t[ty + i * 8][tx] = W[(size_t)(k0 + ty + i * 8) * 1024 + n0 + tx];
    __syncthreads();
#pragma unroll
    for (int i = 0; i < 4; i++)
        WT[(size_t)(n0 + ty + i * 8) * 1024 + k0 + tx] = f2bf(t[tx][ty + i * 8]);
}

// ---------------- fp32 -> bf16 hi/lo elementwise
__global__ __launch_bounds__(256) void conv_split(
    const float* __restrict__ in, u16* __restrict__ oh, u16* __restrict__ ol)
{
    const size_t i = ((size_t)blockIdx.x * 256 + threadIdx.x) * 8;
    short8 rh, rl;
#pragma unroll
    for (int j = 0; j < 8; j++) {
        u16 hi, lo;
        splitbf(in[i + j], hi, lo);
        rh[j] = (short)hi; rl[j] = (short)lo;
    }
    *(short8*)&oh[i] = rh;
    *(short8*)&ol[i] = rl;
}

// ---------------- split bf16 MFMA GEMM: C = (Ah+Al) @ (BTh+BTl)^T (3-term), fp32 out.
__global__ __launch_bounds__(256) void gemm_bf16_split(
    const u16* __restrict__ Ah, const u16* __restrict__ Al,
    const u16* __restrict__ BTh, const u16* __restrict__ BTl,
    float* __restrict__ C, int M, int N, int K)
{
    __shared__ u16 AsH[128 * 32];
    __shared__ u16 AsL[128 * 32];
    __shared__ u16 BsH[128 * 32];
    __shared__ u16 BsL[128 * 32];
    const int tid = threadIdx.x;
    const int lane = tid & 63;
    const int w = tid >> 6;
    const int wr = w >> 1, wc = w & 1;
    const int row0 = blockIdx.y * 128;
    const int col0 = blockIdx.x * 128;
    const int mrow = lane & 15;
    const int kgrp = (lane >> 4) * 8;

    f32x4 acc[4][4] = {};

    const int off0 = w * 1024 + lane * 16;
    const int r0 = off0 >> 6, kl0 = (off0 & 63) >> 1;
    const int off1 = off0 + 4096;
    const int r1 = off1 >> 6, kl1 = (off1 & 63) >> 1;

    for (int kt = 0; kt < K; kt += 32) {
        GLOAD_LDS16(Ah  + (size_t)(row0 + r0) * K + kt + kl0, (char*)AsH + w * 1024);
        GLOAD_LDS16(Ah  + (size_t)(row0 + r1) * K + kt + kl1, (char*)AsH + w * 1024 + 4096);
        GLOAD_LDS16(Al  + (size_t)(row0 + r0) * K + kt + kl0, (char*)AsL + w * 1024);
        GLOAD_LDS16(Al  + (size_t)(row0 + r1) * K + kt + kl1, (char*)AsL + w * 1024 + 4096);
        GLOAD_LDS16(BTh + (size_t)(col0 + r0) * K + kt + kl0, (char*)BsH + w * 1024);
        GLOAD_LDS16(BTh + (size_t)(col0 + r1) * K + kt + kl1, (char*)BsH + w * 1024 + 4096);
        GLOAD_LDS16(BTl + (size_t)(col0 + r0) * K + kt + kl0, (char*)BsL + w * 1024);
        GLOAD_LDS16(BTl + (size_t)(col0 + r1) * K + kt + kl1, (char*)BsL + w * 1024 + 4096);
        __syncthreads();

        short8 aH[4], aL[4], bH[4], bL[4];
#pragma unroll
        for (int mi = 0; mi < 4; ++mi) {
            aH[mi] = *(const short8*)&AsH[(wr * 64 + mi * 16 + mrow) * 32 + kgrp];
            aL[mi] = *(const short8*)&AsL[(wr * 64 + mi * 16 + mrow) * 32 + kgrp];
        }
#pragma unroll
        for (int ni = 0; ni < 4; ++ni) {
            bH[ni] = *(const short8*)&BsH[(wc * 64 + ni * 16 + mrow) * 32 + kgrp];
            bL[ni] = *(const short8*)&BsL[(wc * 64 + ni * 16 + mrow) * 32 + kgrp];
        }
#pragma unroll
        for (int mi = 0; mi < 4; ++mi)
#pragma unroll
            for (int ni = 0; ni < 4; ++ni) {
                acc[mi][ni] = __builtin_amdgcn_mfma_f32_16x16x32_bf16(aH[mi], bH[ni], acc[mi][ni], 0, 0, 0);
                acc[mi][ni] = __builtin_amdgcn_mfma_f32_16x16x32_bf16(aL[mi], bH[ni], acc[mi][ni], 0, 0, 0);
                acc[mi][ni] = __builtin_amdgcn_mfma_f32_16x16x32_bf16(aH[mi], bL[ni], acc[mi][ni], 0, 0, 0);
            }
        __syncthreads();
    }

    const int crow = (lane >> 4) * 4;
#pragma unroll
    for (int mi = 0; mi < 4; ++mi)
#pragma unroll
        for (int ni = 0; ni < 4; ++ni)
#pragma unroll
            for (int j = 0; j < 4; ++j)
                C[(size_t)(row0 + wr * 64 + mi * 16 + crow + j) * N + col0 + wc * 64 + ni * 16 + mrow]
                    = acc[mi][ni][j];
}

// ---------------- plain bf16 MFMA GEMM (final projection)
__global__ __launch_bounds__(256) void gemm_bf16(
    const u16* __restrict__ A, const u16* __restrict__ BT, float* __restrict__ C,
    int M, int N, int K)
{
    __shared__ u16 As[128 * 32];
    __shared__ u16 Bs[128 * 32];
    const int tid = threadIdx.x;
    const int lane = tid & 63;
    const int w = tid >> 6;
    const int wr = w >> 1, wc = w & 1;
    const int row0 = blockIdx.y * 128;
    const int col0 = blockIdx.x * 128;
    const int mrow = lane & 15;
    const int kgrp = (lane >> 4) * 8;

    f32x4 acc[4][4] = {};

    const int off0 = w * 1024 + lane * 16;
    const int r0 = off0 >> 6, kl0 = (off0 & 63) >> 1;
    const int off1 = off0 + 4096;
    const int r1 = off1 >> 6, kl1 = (off1 & 63) >> 1;

    for (int kt = 0; kt < K; kt += 32) {
        GLOAD_LDS16(A  + (size_t)(row0 + r0) * K + kt + kl0, (char*)As + w * 1024);
        GLOAD_LDS16(A  + (size_t)(row0 + r1) * K + kt + kl1, (char*)As + w * 1024 + 4096);
        GLOAD_LDS16(BT + (size_t)(col0 + r0) * K + kt + kl0, (char*)Bs + w * 1024);
        GLOAD_LDS16(BT + (size_t)(col0 + r1) * K + kt + kl1, (char*)Bs + w * 1024 + 4096);
        __syncthreads();

        short8 aF[4], bF[4];
#pragma unroll
        for (int mi = 0; mi < 4; ++mi)
            aF[mi] = *(const short8*)&As[(wr * 64 + mi * 16 + mrow) * 32 + kgrp];
#pragma unroll
        for (int ni = 0; ni < 4; ++ni)
            bF[ni] = *(const short8*)&Bs[(wc * 64 + ni * 16 + mrow) * 32 + kgrp];
#pragma unroll
        for (int mi = 0; mi < 4; ++mi)
#pragma unroll
            for (int ni = 0; ni < 4; ++ni)
                acc[mi][ni] = __builtin_amdgcn_mfma_f32_16x16x32_bf16(aF[mi], bF[ni], acc[mi][ni], 0, 0, 0);
        __syncthreads();
    }

    const int crow = (lane >> 4) * 4;
#pragma unroll
    for (int mi = 0; mi < 4; ++mi)
#pragma unroll
        for (int ni = 0; ni < 4; ++ni)
#pragma unroll
            for (int j = 0; j < 4; ++j)
                C[(size_t)(row0 + wr * 64 + mi * 16 + crow + j) * N + col0 + wc * 64 + ni * 16 + mrow]
                    = acc[mi][ni][j];
}

// ---------------- fp32 GEMM (low-rank paths)
__global__ __launch_bounds__(256) void gemm_f32(
    const float* __restrict__ A, const float* __restrict__ B, float* __restrict__ C,
    int M, int N, int K)
{
    __shared__ float As[16][64];
    __shared__ float Bs[16][64];
    const int tid = threadIdx.x;
    const int row0 = blockIdx.y * 64;
    const int col0 = blockIdx.x * 64;
    const int tx = tid & 15, ty = tid >> 4;
    const int am = tid >> 2, akc = tid & 3;
    const int bkr = tid >> 4, bnc = tid & 15;

    float acc[4][4];
#pragma unroll
    for (int i = 0; i < 4; i++)
#pragma unroll
        for (int j = 0; j < 4; j++) acc[i][j] = 0.f;

    for (int k0 = 0; k0 < K; k0 += 16) {
        float4 av = *(const float4*)&A[(size_t)(row0 + am) * K + k0 + akc * 4];
        float4 bv = *(const float4*)&B[(size_t)(k0 + bkr) * N + col0 + bnc * 4];
        As[akc * 4 + 0][am] = av.x;
        As[akc * 4 + 1][am] = av.y;
        As[akc * 4 + 2][am] = av.z;
        As[akc * 4 + 3][am] = av.w;
        *(float4*)&Bs[bkr][bnc * 4] = bv;
        __syncthreads();
#pragma unroll
        for (int kk = 0; kk < 16; kk++) {
            float4 a = *(const float4*)&As[kk][ty * 4];
            float4 b = *(const float4*)&Bs[kk][tx * 4];
            acc[0][0] += a.x * b.x; acc[0][1] += a.x * b.y; acc[0][2] += a.x * b.z; acc[0][3] += a.x * b.w;
            acc[1][0] += a.y * b.x; acc[1][1] += a.y * b.y; acc[1][2] += a.y * b.z; acc[1][3] += a.y * b.w;
            acc[2][0] += a.z * b.x; acc[2][1] += a.z * b.y; acc[2][2] += a.z * b.z; acc[2][3] += a.z * b.w;
            acc[3][0] += a.w * b.x; acc[3][1] += a.w * b.y; acc[3][2] += a.w * b.z; acc[3][3] += a.w * b.w;
        }
        __syncthreads();
    }
#pragma unroll
    for (int i = 0; i < 4; i++) {
        float4 o = make_float4(acc[i][0], acc[i][1], acc[i][2], acc[i][3]);
        *(float4*)&C[(size_t)(row0 + ty * 4 + i) * N + col0 + tx * 4] = o;
    }
}

// ---------------- prep: one block per (row, h), 128 threads.
__global__ __launch_bounds__(128) void prep_kernel(
    const float* __restrict__ x, const float* __restrict__ Wbeta,
    const float* __restrict__ Wf2, const float* __restrict__ f1,
    const float* __restrict__ qraw, const float* __restrict__ kraw,
    const float* __restrict__ vraw, float* __restrict__ sb)
{
    const int gid = blockIdx.x;
    const int h = gid & 7;
    const int row = gid >> 3;
    const int tid = threadIdx.x;
    const int col = h * 128 + tid;
    const size_t rbase = (size_t)row * 1024;

    __shared__ float f1s[128];
    __shared__ float red[3][128];

    f1s[tid] = f1[(size_t)row * 128 + tid];

    float bsum = 0.f;
#pragma unroll
    for (int i = 0; i < 8; i++)
        bsum += x[rbase + tid + i * 128] * Wbeta[(size_t)(tid + i * 128) * 8 + h];

    float kr = kraw[rbase + col];
    float ksil = siluf(kr);

    red[0][tid] = bsum;
    red[1][tid] = ksil * ksil;
    __syncthreads();

    float fsum = 0.f;
#pragma unroll 8
    for (int i = 0; i < 128; i++) fsum += f1s[i] * Wf2[(size_t)i * 1024 + col];

    for (int off = 64; off > 0; off >>= 1) {
        if (tid < off) {
            red[0][tid] += red[0][tid + off];
            red[1][tid] += red[1][tid + off];
        }
        __syncthreads();
    }
    const float beta = 2.f * sigmf(red[0][0]);
    const float rn = rsqrtf(red[1][0] + 1e-6f);
    __syncthreads();

    const float kn = ksil * rn;
    const float e  = sigmf(fsum);
    const float qs = siluf(qraw[rbase + col]);
    const float vs = siluf(vraw[rbase + col]);
    const float kev = e * kn;
    const float qev = e * qs;

    red[0][tid] = kev * kn;
    red[1][tid] = qs * kev;
    red[2][tid] = qs * kn;
    __syncthreads();
    for (int off = 64; off > 0; off >>= 1) {
        if (tid < off) {
            red[0][tid] += red[0][tid + off];
            red[1][tid] += red[1][tid + off];
            red[2][tid] += red[2][tid + off];
        }
        __syncthreads();
    }

    float* o = sb + (size_t)gid * RECF;
    o[tid]        = kn;
    o[128 + tid]  = e;
    o[256 + tid]  = kev;
    o[384 + tid]  = qev;
    o[512 + tid]  = vs;
    if (tid == 0) {
        o[640] = beta;
        o[641] = red[0][0];
        o[642] = red[1][0];
        o[643] = red[2][0];
    }
}

// ---------------- scan
struct TokR { float4 k, e, ke, qe, sc; float vc; };

__device__ __forceinline__ void load_tok4(const float* __restrict__ vb, int rg, int col, TokR& T)
{
    const float4* p4 = (const float4*)vb;
    T.k = p4[rg]; T.e = p4[32 + rg]; T.ke = p4[64 + rg]; T.qe = p4[96 + rg];
    T.sc = p4[160];
    T.vc = vb[512 + col];
}

// 32-lane sum: 4 DPP stages (within 16) + ds_swizzle xor16 (within 32).
__device__ __forceinline__ float red32(float x)
{
    x += __int_as_float(__builtin_amdgcn_mov_dpp(__float_as_int(x), 0xB1,  0xF, 0xF, true));
    x += __int_as_float(__builtin_amdgcn_mov_dpp(__float_as_int(x), 0x4E,  0xF, 0xF, true));
    x += __int_as_float(__builtin_amdgcn_mov_dpp(__float_as_int(x), 0x141, 0xF, 0xF, true));
    x += __int_as_float(__builtin_amdgcn_mov_dpp(__float_as_int(x), 0x140, 0xF, 0xF, true));
    x += __int_as_float(__builtin_amdgcn_ds_swizzle(__float_as_int(x), 0x401F));
    return x;
}

#define SCAN_STEP4(T, OUTIDX)                                                   \
  {                                                                             \
    float bS  = (T.k.x  * S0 + T.k.y  * S1) + (T.k.z  * S2 + T.k.w  * S3);      \
    float keS = (T.ke.x * S0 + T.ke.y * S1) + (T.ke.z * S2 + T.ke.w * S3);      \
    float qeS = (T.qe.x * S0 + T.qe.y * S1) + (T.qe.z * S2 + T.qe.w * S3);      \
    bS = red32(bS); keS = red32(keS); qeS = red32(qeS);                         \
    const float bSb = T.sc.x * bS;                                              \
    const float ks  = keS - bSb * T.sc.y;                                       \
    const float w   = T.vc - T.sc.x * ks;                                       \
    const float o   = (qeS - bSb * T.sc.z) + w * T.sc.w;                        \
    S0 = (T.e.x * S0 - bSb * T.ke.x) + w * T.k.x;                               \
    S1 = (T.e.y * S1 - bSb * T.ke.y) + w * T.k.y;                               \
    S2 = (T.e.z * S2 - bSb * T.ke.z) + w * T.k.z;                               \
    S3 = (T.e.w * S3 - bSb * T.ke.w) + w * T.k.w;                               \
    if (rg == 0) ov[OUTIDX] = o;                                                \
  }

#define SBAR __builtin_amdgcn_sched_barrier(0)

__device__ __forceinline__ const float* recp(const float* p0, int t)
{
    const int tc = (t < 2048) ? t : 2047;
    return p0 + (size_t)tc * RECSTRIDE;
}

// 256 blocks x 256 threads (4 waves); 8 cols/block, 32 lanes/col, 4 rows/lane.
// 8-deep register prefetch, issue order pinned with sched_barrier(0) so the
// compiler cannot sink the loads to their uses (R5 post-mortem: VGPR=52 proved
// it had deleted the pipeline).
__global__ __launch_bounds__(256) void scan_kernel(
    const float* __restrict__ sb, float* __restrict__ ov)
{
    const int tid = threadIdx.x;
    const int blk = blockIdx.x;
    const int bh = blk >> 4;
    const int cg = blk & 15;
    const int b = bh >> 3, h = bh & 7;
    const int cl = tid >> 5;
    const int rg = tid & 31;
    const int col = cg * 8 + cl;

    float S0 = 0.f, S1 = 0.f, S2 = 0.f, S3 = 0.f;

    const size_t base = (size_t)b * 2048 * 8 + h;
    const float* p0 = sb + base * RECF;
    size_t oidx = base * 128 + col;

    TokR R0, R1, R2, R3, R4, R5, R6, R7;
    load_tok4(recp(p0, 0), rg, col, R0); SBAR;
    load_tok4(recp(p0, 1), rg, col, R1); SBAR;
    load_tok4(recp(p0, 2), rg, col, R2); SBAR;
    load_tok4(recp(p0, 3), rg, col, R3); SBAR;
    load_tok4(recp(p0, 4), rg, col, R4); SBAR;
    load_tok4(recp(p0, 5), rg, col, R5); SBAR;
    load_tok4(recp(p0, 6), rg, col, R6); SBAR;
    load_tok4(recp(p0, 7), rg, col, R7); SBAR;

    for (int t = 0; t < 2048; t += 8) {
        SCAN_STEP4(R0, oidx);
        load_tok4(recp(p0, t + 8), rg, col, R0); SBAR;
        SCAN_STEP4(R1, oidx + 1024);
        load_tok4(recp(p0, t + 9), rg, col, R1); SBAR;
        SCAN_STEP4(R2, oidx + 2048);
        load_tok4(recp(p0, t + 10), rg, col, R2); SBAR;
        SCAN_STEP4(R3, oidx + 3072);
        load_tok4(recp(p0, t + 11), rg, col, R3); SBAR;
        SCAN_STEP4(R4, oidx + 4096);
        load_tok4(recp(p0, t + 12), rg, col, R4); SBAR;
        SCAN_STEP4(R5, oidx + 5120);
        load_tok4(recp(p0, t + 13), rg, col, R5); SBAR;
        SCAN_STEP4(R6, oidx + 6144);
        load_tok4(recp(p0, t + 14), rg, col, R6); SBAR;
        SCAN_STEP4(R7, oidx + 7168);
        load_tok4(recp(p0, t + 15), rg, col, R7); SBAR;
        oidx += 8192;
    }
}

// ---------------- post: writes bf16 y
__global__ __launch_bounds__(128) void post_kernel(
    const float* __restrict__ ov, const float* __restrict__ og1,
    const float* __restrict__ Wog2, const float* __restrict__ normw,
    u16* __restrict__ ybf)
{
    const int gid = blockIdx.x;
    const int h = gid & 7;
    const int row = gid >> 3;
    const int tid = threadIdx.x;
    const int col = h * 128 + tid;

    __shared__ float ogs[128];
    __shared__ float red[128];

    ogs[tid] = og1[(size_t)row * 128 + tid];
    __syncthreads();

    float g = 0.f;
#pragma unroll 8
    for (int i = 0; i < 128; i++) g += ogs[i] * Wog2[(size_t)i * 1024 + col];

    const float o = ov[(size_t)row * 1024 + col];
    const float y = o * sigmf(g);

    red[tid] = y * y;
    __syncthreads();
    for (int off = 64; off > 0; off >>= 1) {
        if (tid < off) red[tid] += red[tid + off];
        __syncthreads();
    }
    const float rms = rsqrtf(red[0] * (1.f / 128.f) + 1e-6f);
    ybf[(size_t)row * 1024 + col] = f2bf(y * rms * normw[col]);
}

extern "C" void kernel_launch(void* const* d_in, const int* in_sizes, int n_in,
                              void* d_out, int out_size, void* d_ws, size_t ws_size,
                              hipStream_t stream)
{
    const float* x     = (const float*)d_in[0];
    const float* Wq    = (const float*)d_in[1];
    const float* Wk    = (const float*)d_in[2];
    const float* Wv    = (const float*)d_in[3];
    const float* Wf1   = (const float*)d_in[4];
    const float* Wf2   = (const float*)d_in[5];
    const float* Wbeta = (const float*)d_in[6];
    const float* Wog1  = (const float*)d_in[7];
    const float* Wog2  = (const float*)d_in[8];
    const float* normw = (const float*)d_in[9];
    const float* Wo    = (const float*)d_in[10];
    float* out = (float*)d_out;

    float* ws   = (float*)d_ws;
    float* qraw = ws;                                 // 4M floats
    float* kraw = ws + SZT;
    float* vraw = ws + 2 * SZT;
    float* sb   = ws + 3 * SZT;                       // 32768*656 floats
    float* ov   = sb + (size_t)32768 * RECF;          // 4M floats; WT hi/lo live here early
    float* f1   = ov + SZT;                           // 0.5M
    float* og1  = f1 + (size_t)4096 * 128;            // 0.5M
    float* xsp  = og1 + (size_t)4096 * 128;           // 4M floats (xh, xl as u16)
    float* wot  = xsp + SZT;                          // 0.5M floats (WoT)

    u16* xh  = (u16*)xsp;                             // 4M u16
    u16* xl  = xh + SZT;                              // 4M u16
    u16* WoT = (u16*)wot;

    u16* WqTh = (u16*)ov;                             // 6 x 1M u16 inside ov
    u16* WqTl = WqTh + (size_t)1024 * 1024;
    u16* WkTh = WqTl + (size_t)1024 * 1024;
    u16* WkTl = WkTh + (size_t)1024 * 1024;
    u16* WvTh = WkTl + (size_t)1024 * 1024;
    u16* WvTl = WvTh + (size_t)1024 * 1024;

    u16* ybf = (u16*)vraw;                            // vraw dead after prep

    dim3 b256(256), b128(128);

    wtrans_split<<<dim3(32, 32), b256, 0, stream>>>(Wq, WqTh, WqTl);
    wtrans_split<<<dim3(32, 32), b256, 0, stream>>>(Wk, WkTh, WkTl);
    wtrans_split<<<dim3(32, 32), b256, 0, stream>>>(Wv, WvTh, WvTl);
    wtrans<<<dim3(32, 32), b256, 0, stream>>>(Wo, WoT);
    conv_split<<<2048, b256, 0, stream>>>(x, xh, xl);

    gemm_bf16_split<<<dim3(8, 32), b256, 0, stream>>>(xh, xl, WqTh, WqTl, qraw, 4096, 1024, 1024);
    gemm_bf16_split<<<dim3(8, 32), b256, 0, stream>>>(xh, xl, WkTh, WkTl, kraw, 4096, 1024, 1024);
    gemm_bf16_split<<<dim3(8, 32), b256, 0, stream>>>(xh, xl, WvTh, WvTl, vraw, 4096, 1024, 1024);
    gemm_f32<<<dim3(2, 64),  b256, 0, stream>>>(x, Wf1, f1,  4096, 128, 1024);
    gemm_f32<<<dim3(2, 64),  b256, 0, stream>>>(x, Wog1, og1, 4096, 128, 1024);

    prep_kernel<<<32768, b128, 0, stream>>>(x, Wbeta, Wf2, f1, qraw, kraw, vraw, sb);
    scan_kernel<<<256, b256, 0, stream>>>(sb, ov);
    post_kernel<<<32768, b128, 0, stream>>>(ov, og1, Wog2, normw, ybf);

    gemm_bf16<<<dim3(8, 32), b256, 0, stream>>>(ybf, WoT, out, 4096, 1024, 1024);
}

// Round 8
// 1129.356 us; speedup vs baseline: 2.0501x; 1.0773x over previous
//
#include <hip/hip_runtime.h>
#include <cmath>

// DenseRnn on MI355X. Shapes: B=2, N=2048, D=1024, H=8, HD=128.
//
//  1. wtrans_split: Wq/Wk/Wv fp32 [K][N] -> bf16 hi+lo WT [N][K]; Wo -> plain bf16 WT
//     conv_split: x -> bf16 hi+lo
//  2. gemm_bf16_split (MFMA 16x16x32, 3-term bf16x2): qraw/kraw/vraw = x@W, ~fp32 accuracy
//  3. gemm_f32 x@Wf1 -> f1; x@Wog1 -> og1 (low-rank, fp32)
//  4. prep: silu/l2norm/beta/e, pack per-(row,h) record + fused scalars
//  5. scan: per-column recurrence, 32 lanes/col x 4 rows/lane, DPP+swizzle
//     reductions. Token records staged via global_load_lds (PER-LANE global
//     src = src + lane*16 -- R7 bug was a uniform src) into a double-buffered
//     8-token LDS ring; block decode keeps one (b,h) stream on one XCD.
//  6. post: gate, sigmoid, per-head RMS, *norm_w -> bf16 y
//  7. gemm_bf16 y@Wo -> out (plain bf16: no recurrence amplification here)

#define SZT ((size_t)4096 * 1024)
#define RECF 656
#define RECSTRIDE 5248     // 8*RECF floats between consecutive tokens of a stream
#define TOKB 8             // tokens per staged batch
#define SLOTB 2112         // LDS bytes per token slot (2048 k/e/ke/qe + 32 v + 16 sc + pad)

typedef unsigned short u16;
typedef __attribute__((ext_vector_type(8))) short short8;
typedef __attribute__((ext_vector_type(4))) float f32x4;

__device__ __forceinline__ float sigmf(float x) { return 1.f / (1.f + expf(-x)); }
__device__ __forceinline__ float siluf(float x) { return x * sigmf(x); }
__device__ __forceinline__ u16 f2bf(float f) {
    unsigned int u = __float_as_uint(f);
    unsigned int r = (u + 0x7FFFu + ((u >> 16) & 1u)) >> 16;
    return (u16)r;
}
__device__ __forceinline__ float bf2f(u16 h) { return __uint_as_float((unsigned int)h << 16); }
__device__ __forceinline__ void splitbf(float f, u16& hi, u16& lo) {
    hi = f2bf(f);
    lo = f2bf(f - bf2f(hi));
}

#define GLOAD_LDS16(gp, lp) __builtin_amdgcn_global_load_lds( \
    (const __attribute__((address_space(1))) void*)(gp),      \
    (__attribute__((address_space(3))) void*)(lp), 16, 0, 0)

// ---------------- transpose+convert (split): W fp32 [1024][1024] -> hi/lo bf16 [N][K]
__global__ __launch_bounds__(256) void wtrans_split(
    const float* __restrict__ W, u16* __restrict__ WTh, u16* __restrict__ WTl)
{
    __shared__ float t[32][33];
    const int tx = threadIdx.x & 31, ty = threadIdx.x >> 5;
    const int n0 = blockIdx.x * 32, k0 = blockIdx.y * 32;
#pragma unroll
    for (int i = 0; i < 4; i++)
        t[ty + i * 8][tx] = W[(size_t)(k0 + ty + i * 8) * 1024 + n0 + tx];
    __syncthreads();
#pragma unroll
    for (int i = 0; i < 4; i++) {
        u16 hi, lo;
        splitbf(t[tx][ty + i * 8], hi, lo);
        WTh[(size_t)(n0 + ty + i * 8) * 1024 + k0 + tx] = hi;
        WTl[(size_t)(n0 + ty + i * 8) * 1024 + k0 + tx] = lo;
    }
}

// ---------------- transpose+convert (plain)
__global__ __launch_bounds__(256) void wtrans(const float* __restrict__ W, u16* __restrict__ WT)
{
    __shared__ float t[32][33];
    const int tx = threadIdx.x & 31, ty = threadIdx.x >> 5;
    const int n0 = blockIdx.x * 32, k0 = blockIdx.y * 32;
#pragma unroll
    for (int i = 0; i < 4; i++)
        t[ty + i * 8][tx] = W[(size_t)(k0 + ty + i * 8) * 1024 + n0 + tx];
    __syncthreads();
#pragma unroll
    for (int i = 0; i < 4; i++)
        WT[(size_t)(n0 + ty + i * 8) * 1024 + k0 + tx] = f2bf(t[tx][ty + i * 8]);
}

// ---------------- fp32 -> bf16 hi/lo elementwise
__global__ __launch_bounds__(256) void conv_split(
    const float* __restrict__ in, u16* __restrict__ oh, u16* __restrict__ ol)
{
    const size_t i = ((size_t)blockIdx.x * 256 + threadIdx.x) * 8;
    short8 rh, rl;
#pragma unroll
    for (int j = 0; j < 8; j++) {
        u16 hi, lo;
        splitbf(in[i + j], hi, lo);
        rh[j] = (short)hi; rl[j] = (short)lo;
    }
    *(short8*)&oh[i] = rh;
    *(short8*)&ol[i] = rl;
}

// ---------------- split bf16 MFMA GEMM: C = (Ah+Al) @ (BTh+BTl)^T (3-term), fp32 out.
__global__ __launch_bounds__(256) void gemm_bf16_split(
    const u16* __restrict__ Ah, const u16* __restrict__ Al,
    const u16* __restrict__ BTh, const u16* __restrict__ BTl,
    float* __restrict__ C, int M, int N, int K)
{
    __shared__ u16 AsH[128 * 32];
    __shared__ u16 AsL[128 * 32];
    __shared__ u16 BsH[128 * 32];
    __shared__ u16 BsL[128 * 32];
    const int tid = threadIdx.x;
    const int lane = tid & 63;
    const int w = tid >> 6;
    const int wr = w >> 1, wc = w & 1;
    const int row0 = blockIdx.y * 128;
    const int col0 = blockIdx.x * 128;
    const int mrow = lane & 15;
    const int kgrp = (lane >> 4) * 8;

    f32x4 acc[4][4] = {};

    const int off0 = w * 1024 + lane * 16;
    const int r0 = off0 >> 6, kl0 = (off0 & 63) >> 1;
    const int off1 = off0 + 4096;
    const int r1 = off1 >> 6, kl1 = (off1 & 63) >> 1;

    for (int kt = 0; kt < K; kt += 32) {
        GLOAD_LDS16(Ah  + (size_t)(row0 + r0) * K + kt + kl0, (char*)AsH + w * 1024);
        GLOAD_LDS16(Ah  + (size_t)(row0 + r1) * K + kt + kl1, (char*)AsH + w * 1024 + 4096);
        GLOAD_LDS16(Al  + (size_t)(row0 + r0) * K + kt + kl0, (char*)AsL + w * 1024);
        GLOAD_LDS16(Al  + (size_t)(row0 + r1) * K + kt + kl1, (char*)AsL + w * 1024 + 4096);
        GLOAD_LDS16(BTh + (size_t)(col0 + r0) * K + kt + kl0, (char*)BsH + w * 1024);
        GLOAD_LDS16(BTh + (size_t)(col0 + r1) * K + kt + kl1, (char*)BsH + w * 1024 + 4096);
        GLOAD_LDS16(BTl + (size_t)(col0 + r0) * K + kt + kl0, (char*)BsL + w * 1024);
        GLOAD_LDS16(BTl + (size_t)(col0 + r1) * K + kt + kl1, (char*)BsL + w * 1024 + 4096);
        __syncthreads();

        short8 aH[4], aL[4], bH[4], bL[4];
#pragma unroll
        for (int mi = 0; mi < 4; ++mi) {
            aH[mi] = *(const short8*)&AsH[(wr * 64 + mi * 16 + mrow) * 32 + kgrp];
            aL[mi] = *(const short8*)&AsL[(wr * 64 + mi * 16 + mrow) * 32 + kgrp];
        }
#pragma unroll
        for (int ni = 0; ni < 4; ++ni) {
            bH[ni] = *(const short8*)&BsH[(wc * 64 + ni * 16 + mrow) * 32 + kgrp];
            bL[ni] = *(const short8*)&BsL[(wc * 64 + ni * 16 + mrow) * 32 + kgrp];
        }
#pragma unroll
        for (int mi = 0; mi < 4; ++mi)
#pragma unroll
            for (int ni = 0; ni < 4; ++ni) {
                acc[mi][ni] = __builtin_amdgcn_mfma_f32_16x16x32_bf16(aH[mi], bH[ni], acc[mi][ni], 0, 0, 0);
                acc[mi][ni] = __builtin_amdgcn_mfma_f32_16x16x32_bf16(aL[mi], bH[ni], acc[mi][ni], 0, 0, 0);
                acc[mi][ni] = __builtin_amdgcn_mfma_f32_16x16x32_bf16(aH[mi], bL[ni], acc[mi][ni], 0, 0, 0);
            }
        __syncthreads();
    }

    const int crow = (lane >> 4) * 4;
#pragma unroll
    for (int mi = 0; mi < 4; ++mi)
#pragma unroll
        for (int ni = 0; ni < 4; ++ni)
#pragma unroll
            for (int j = 0; j < 4; ++j)
                C[(size_t)(row0 + wr * 64 + mi * 16 + crow + j) * N + col0 + wc * 64 + ni * 16 + mrow]
                    = acc[mi][ni][j];
}

// ---------------- plain bf16 MFMA GEMM (final projection)
__global__ __launch_bounds__(256) void gemm_bf16(
    const u16* __restrict__ A, const u16* __restrict__ BT, float* __restrict__ C,
    int M, int N, int K)
{
    __shared__ u16 As[128 * 32];
    __shared__ u16 Bs[128 * 32];
    const int tid = threadIdx.x;
    const int lane = tid & 63;
    const int w = tid >> 6;
    const int wr = w >> 1, wc = w & 1;
    const int row0 = blockIdx.y * 128;
    const int col0 = blockIdx.x * 128;
    const int mrow = lane & 15;
    const int kgrp = (lane >> 4) * 8;

    f32x4 acc[4][4] = {};

    const int off0 = w * 1024 + lane * 16;
    const int r0 = off0 >> 6, kl0 = (off0 & 63) >> 1;
    const int off1 = off0 + 4096;
    const int r1 = off1 >> 6, kl1 = (off1 & 63) >> 1;

    for (int kt = 0; kt < K; kt += 32) {
        GLOAD_LDS16(A  + (size_t)(row0 + r0) * K + kt + kl0, (char*)As + w * 1024);
        GLOAD_LDS16(A  + (size_t)(row0 + r1) * K + kt + kl1, (char*)As + w * 1024 + 4096);
        GLOAD_LDS16(BT + (size_t)(col0 + r0) * K + kt + kl0, (char*)Bs + w * 1024);
        GLOAD_LDS16(BT + (size_t)(col0 + r1) * K + kt + kl1, (char*)Bs + w * 1024 + 4096);
        __syncthreads();

        short8 aF[4], bF[4];
#pragma unroll
        for (int mi = 0; mi < 4; ++mi)
            aF[mi] = *(const short8*)&As[(wr * 64 + mi * 16 + mrow) * 32 + kgrp];
#pragma unroll
        for (int ni = 0; ni < 4; ++ni)
            bF[ni] = *(const short8*)&Bs[(wc * 64 + ni * 16 + mrow) * 32 + kgrp];
#pragma unroll
        for (int mi = 0; mi < 4; ++mi)
#pragma unroll
            for (int ni = 0; ni < 4; ++ni)
                acc[mi][ni] = __builtin_amdgcn_mfma_f32_16x16x32_bf16(aF[mi], bF[ni], acc[mi][ni], 0, 0, 0);
        __syncthreads();
    }

    const int crow = (lane >> 4) * 4;
#pragma unroll
    for (int mi = 0; mi < 4; ++mi)
#pragma unroll
        for (int ni = 0; ni < 4; ++ni)
#pragma unroll
            for (int j = 0; j < 4; ++j)
                C[(size_t)(row0 + wr * 64 + mi * 16 + crow + j) * N + col0 + wc * 64 + ni * 16 + mrow]
                    = acc[mi][ni][j];
}

// ---------------- fp32 GEMM (low-rank paths)
__global__ __launch_bounds__(256) void gemm_f32(
    const float* __restrict__ A, const float* __restrict__ B, float* __restrict__ C,
    int M, int N, int K)
{
    __shared__ float As[16][64];
    __shared__ float Bs[16][64];
    const int tid = threadIdx.x;
    const int row0 = blockIdx.y * 64;
    const int col0 = blockIdx.x * 64;
    const int tx = tid & 15, ty = tid >> 4;
    const int am = tid >> 2, akc = tid & 3;
    const int bkr = tid >> 4, bnc = tid & 15;

    float acc[4][4];
#pragma unroll
    for (int i = 0; i < 4; i++)
#pragma unroll
        for (int j = 0; j < 4; j++) acc[i][j] = 0.f;

    for (int k0 = 0; k0 < K; k0 += 16) {
        float4 av = *(const float4*)&A[(size_t)(row0 + am) * K + k0 + akc * 4];
        float4 bv = *(const float4*)&B[(size_t)(k0 + bkr) * N + col0 + bnc * 4];
        As[akc * 4 + 0][am] = av.x;
        As[akc * 4 + 1][am] = av.y;
        As[akc * 4 + 2][am] = av.z;
        As[akc * 4 + 3][am] = av.w;
        *(float4*)&Bs[bkr][bnc * 4] = bv;
        __syncthreads();
#pragma unroll
        for (int kk = 0; kk < 16; kk++) {
            float4 a = *(const float4*)&As[kk][ty * 4];
            float4 b = *(const float4*)&Bs[kk][tx * 4];
            acc[0][0] += a.x * b.x; acc[0][1] += a.x * b.y; acc[0][2] += a.x * b.z; acc[0][3] += a.x * b.w;
            acc[1][0] += a.y * b.x; acc[1][1] += a.y * b.y; acc[1][2] += a.y * b.z; acc[1][3] += a.y * b.w;
            acc[2][0] += a.z * b.x; acc[2][1] += a.z * b.y; acc[2][2] += a.z * b.z; acc[2][3] += a.z * b.w;
            acc[3][0] += a.w * b.x; acc[3][1] += a.w * b.y; acc[3][2] += a.w * b.z; acc[3][3] += a.w * b.w;
        }
        __syncthreads();
    }
#pragma unroll
    for (int i = 0; i < 4; i++) {
        float4 o = make_float4(acc[i][0], acc[i][1], acc[i][2], acc[i][3]);
        *(float4*)&C[(size_t)(row0 + ty * 4 + i) * N + col0 + tx * 4] = o;
    }
}

// ---------------- prep: one block per (row, h), 128 threads.
__global__ __launch_bounds__(128) void prep_kernel(
    const float* __restrict__ x, const float* __restrict__ Wbeta,
    const float* __restrict__ Wf2, const float* __restrict__ f1,
    const float* __restrict__ qraw, const float* __restrict__ kraw,
    const float* __restrict__ vraw, float* __restrict__ sb)
{
    const int gid = blockIdx.x;
    const int h = gid & 7;
    const int row = gid >> 3;
    const int tid = threadIdx.x;
    const int col = h * 128 + tid;
    const size_t rbase = (size_t)row * 1024;

    __shared__ float f1s[128];
    __shared__ float red[3][128];

    f1s[tid] = f1[(size_t)row * 128 + tid];

    float bsum = 0.f;
#pragma unroll
    for (int i = 0; i < 8; i++)
        bsum += x[rbase + tid + i * 128] * Wbeta[(size_t)(tid + i * 128) * 8 + h];

    float kr = kraw[rbase + col];
    float ksil = siluf(kr);

    red[0][tid] = bsum;
    red[1][tid] = ksil * ksil;
    __syncthreads();

    float fsum = 0.f;
#pragma unroll 8
    for (int i = 0; i < 128; i++) fsum += f1s[i] * Wf2[(size_t)i * 1024 + col];

    for (int off = 64; off > 0; off >>= 1) {
        if (tid < off) {
            red[0][tid] += red[0][tid + off];
            red[1][tid] += red[1][tid + off];
        }
        __syncthreads();
    }
    const float beta = 2.f * sigmf(red[0][0]);
    const float rn = rsqrtf(red[1][0] + 1e-6f);
    __syncthreads();

    const float kn = ksil * rn;
    const float e  = sigmf(fsum);
    const float qs = siluf(qraw[rbase + col]);
    const float vs = siluf(vraw[rbase + col]);
    const float kev = e * kn;
    const float qev = e * qs;

    red[0][tid] = kev * kn;
    red[1][tid] = qs * kev;
    red[2][tid] = qs * kn;
    __syncthreads();
    for (int off = 64; off > 0; off >>= 1) {
        if (tid < off) {
            red[0][tid] += red[0][tid + off];
            red[1][tid] += red[1][tid + off];
            red[2][tid] += red[2][tid + off];
        }
        __syncthreads();
    }

    float* o = sb + (size_t)gid * RECF;
    o[tid]        = kn;
    o[128 + tid]  = e;
    o[256 + tid]  = kev;
    o[384 + tid]  = qev;
    o[512 + tid]  = vs;
    if (tid == 0) {
        o[640] = beta;
        o[641] = red[0][0];
        o[642] = red[1][0];
        o[643] = red[2][0];
    }
}

// ---------------- scan
// 32-lane sum: 4 DPP stages (within 16) + ds_swizzle xor16 (within 32).
__device__ __forceinline__ float red32(float x)
{
    x += __int_as_float(__builtin_amdgcn_mov_dpp(__float_as_int(x), 0xB1,  0xF, 0xF, true));
    x += __int_as_float(__builtin_amdgcn_mov_dpp(__float_as_int(x), 0x4E,  0xF, 0xF, true));
    x += __int_as_float(__builtin_amdgcn_mov_dpp(__float_as_int(x), 0x141, 0xF, 0xF, true));
    x += __int_as_float(__builtin_amdgcn_mov_dpp(__float_as_int(x), 0x140, 0xF, 0xF, true));
    x += __int_as_float(__builtin_amdgcn_ds_swizzle(__float_as_int(x), 0x401F));
    return x;
}

// Stage TOKB token records into an LDS batch buffer via async global_load_lds.
// global_load_lds: LDS dest = uniform base + lane*16; global src is PER-LANE,
// so each lane supplies src + lane*16 (R7's bug: uniform src replicated one
// 16B chunk across the slot). Wave w stages slots s == w (mod 4).
__device__ __forceinline__ void stage_batch(
    const float* __restrict__ p0, char* ldsbuf, int t0, int w, int lane, int cg)
{
    for (int s = w; s < TOKB; s += 4) {
        const char* src = (const char*)(p0 + (size_t)(t0 + s) * RECSTRIDE);
        char* dst = ldsbuf + s * SLOTB;
        GLOAD_LDS16(src + lane * 16,        dst);           // k,e      (1024B)
        GLOAD_LDS16(src + 1024 + lane * 16, dst + 1024);    // ke,qe    (1024B)
        if (lane < 2)
            GLOAD_LDS16(src + 2048 + cg * 32 + lane * 16, dst + 2048); // v slice (32B)
        if (lane == 0)
            GLOAD_LDS16(src + 2560, dst + 2080);            // scalars  (16B)
    }
}

// 256 blocks x 256 threads (4 waves); 8 cols/block, 32 lanes/col, 4 rows/lane.
// Block decode: bh = blk&15 so the 16 blocks of one (b,h) stream sit on one
// XCD (blk%8 constant) -> record re-reads hit that XCD's L2.
__global__ __launch_bounds__(256) void scan_kernel(
    const float* __restrict__ sb, float* __restrict__ ov)
{
    __shared__ char lds[2 * TOKB * SLOTB];

    const int tid = threadIdx.x;
    const int blk = blockIdx.x;
    const int bh = blk & 15;
    const int cg = blk >> 4;
    const int b = bh >> 3, h = bh & 7;
    const int cl = tid >> 5;
    const int rg = tid & 31;
    const int col = cg * 8 + cl;
    const int w = tid >> 6;
    const int lane = tid & 63;

    float S0 = 0.f, S1 = 0.f, S2 = 0.f, S3 = 0.f;

    const size_t base = (size_t)b * 2048 * 8 + h;
    const float* p0 = sb + base * RECF;
    size_t oidx = base * 128 + col;

    stage_batch(p0, lds, 0, w, lane, cg);
    __syncthreads();

    int cur = 0;
    for (int t0 = 0; t0 < 2048; t0 += TOKB) {
        if (t0 + TOKB < 2048)
            stage_batch(p0, lds + (cur ^ 1) * (TOKB * SLOTB), t0 + TOKB, w, lane, cg);

        const char* bufp = lds + cur * (TOKB * SLOTB);
#pragma unroll
        for (int s = 0; s < TOKB; ++s) {
            const char* rec = bufp + s * SLOTB;
            const float4 k  = *(const float4*)(rec + (rg << 4));
            const float4 e  = *(const float4*)(rec + 512  + (rg << 4));
            const float4 ke = *(const float4*)(rec + 1024 + (rg << 4));
            const float4 qe = *(const float4*)(rec + 1536 + (rg << 4));
            const float4 sc = *(const float4*)(rec + 2080);
            const float  vc = *(const float*)(rec + 2048 + (cl << 2));

            float bS  = (k.x  * S0 + k.y  * S1) + (k.z  * S2 + k.w  * S3);
            float keS = (ke.x * S0 + ke.y * S1) + (ke.z * S2 + ke.w * S3);
            float qeS = (qe.x * S0 + qe.y * S1) + (qe.z * S2 + qe.w * S3);
            bS = red32(bS); keS = red32(keS); qeS = red32(qeS);
            const float bSb = sc.x * bS;
            const float ks  = keS - bSb * sc.y;
            const float wv  = vc - sc.x * ks;
            const float o   = (qeS - bSb * sc.z) + wv * sc.w;
            S0 = (e.x * S0 - bSb * ke.x) + wv * k.x;
            S1 = (e.y * S1 - bSb * ke.y) + wv * k.y;
            S2 = (e.z * S2 - bSb * ke.z) + wv * k.z;
            S3 = (e.w * S3 - bSb * ke.w) + wv * k.w;
            if (rg == 0) ov[oidx + (size_t)s * 1024] = o;
        }
        __syncthreads();
        cur ^= 1;
        oidx += (size_t)TOKB * 1024;
    }
}

// ---------------- post: writes bf16 y
__global__ __launch_bounds__(128) void post_kernel(
    const float* __restrict__ ov, const float* __restrict__ og1,
    const float* __restrict__ Wog2, const float* __restrict__ normw,
    u16* __restrict__ ybf)
{
    const int gid = blockIdx.x;
    const int h = gid & 7;
    const int row = gid >> 3;
    const int tid = threadIdx.x;
    const int col = h * 128 + tid;

    __shared__ float ogs[128];
    __shared__ float red[128];

    ogs[tid] = og1[(size_t)row * 128 + tid];
    __syncthreads();

    float g = 0.f;
#pragma unroll 8
    for (int i = 0; i < 128; i++) g += ogs[i] * Wog2[(size_t)i * 1024 + col];

    const float o = ov[(size_t)row * 1024 + col];
    const float y = o * sigmf(g);

    red[tid] = y * y;
    __syncthreads();
    for (int off = 64; off > 0; off >>= 1) {
        if (tid < off) red[tid] += red[tid + off];
        __syncthreads();
    }
    const float rms = rsqrtf(red[0] * (1.f / 128.f) + 1e-6f);
    ybf[(size_t)row * 1024 + col] = f2bf(y * rms * normw[col]);
}

extern "C" void kernel_launch(void* const* d_in, const int* in_sizes, int n_in,
                              void* d_out, int out_size, void* d_ws, size_t ws_size,
                              hipStream_t stream)
{
    const float* x     = (const float*)d_in[0];
    const float* Wq    = (const float*)d_in[1];
    const float* Wk    = (const float*)d_in[2];
    const float* Wv    = (const float*)d_in[3];
    const float* Wf1   = (const float*)d_in[4];
    const float* Wf2   = (const float*)d_in[5];
    const float* Wbeta = (const float*)d_in[6];
    const float* Wog1  = (const float*)d_in[7];
    const float* Wog2  = (const float*)d_in[8];
    const float* normw = (const float*)d_in[9];
    const float* Wo    = (const float*)d_in[10];
    float* out = (float*)d_out;

    float* ws   = (float*)d_ws;
    float* qraw = ws;                                 // 4M floats
    float* kraw = ws + SZT;
    float* vraw = ws + 2 * SZT;
    float* sb   = ws + 3 * SZT;                       // 32768*656 floats
    float* ov   = sb + (size_t)32768 * RECF;          // 4M floats; WT hi/lo live here early
    float* f1   = ov + SZT;                           // 0.5M
    float* og1  = f1 + (size_t)4096 * 128;            // 0.5M
    float* xsp  = og1 + (size_t)4096 * 128;           // 4M floats (xh, xl as u16)
    float* wot  = xsp + SZT;                          // 0.5M floats (WoT)

    u16* xh  = (u16*)xsp;                             // 4M u16
    u16* xl  = xh + SZT;                              // 4M u16
    u16* WoT = (u16*)wot;

    u16* WqTh = (u16*)ov;                             // 6 x 1M u16 inside ov
    u16* WqTl = WqTh + (size_t)1024 * 1024;
    u16* WkTh = WqTl + (size_t)1024 * 1024;
    u16* WkTl = WkTh + (size_t)1024 * 1024;
    u16* WvTh = WkTl + (size_t)1024 * 1024;
    u16* WvTl = WvTh + (size_t)1024 * 1024;

    u16* ybf = (u16*)vraw;                            // vraw dead after prep

    dim3 b256(256), b128(128);

    wtrans_split<<<dim3(32, 32), b256, 0, stream>>>(Wq, WqTh, WqTl);
    wtrans_split<<<dim3(32, 32), b256, 0, stream>>>(Wk, WkTh, WkTl);
    wtrans_split<<<dim3(32, 32), b256, 0, stream>>>(Wv, WvTh, WvTl);
    wtrans<<<dim3(32, 32), b256, 0, stream>>>(Wo, WoT);
    conv_split<<<2048, b256, 0, stream>>>(x, xh, xl);

    gemm_bf16_split<<<dim3(8, 32), b256, 0, stream>>>(xh, xl, WqTh, WqTl, qraw, 4096, 1024, 1024);
    gemm_bf16_split<<<dim3(8, 32), b256, 0, stream>>>(xh, xl, WkTh, WkTl, kraw, 4096, 1024, 1024);
    gemm_bf16_split<<<dim3(8, 32), b256, 0, stream>>>(xh, xl, WvTh, WvTl, vraw, 4096, 1024, 1024);
    gemm_f32<<<dim3(2, 64),  b256, 0, stream>>>(x, Wf1, f1,  4096, 128, 1024);
    gemm_f32<<<dim3(2, 64),  b256, 0, stream>>>(x, Wog1, og1, 4096, 128, 1024);

    prep_kernel<<<32768, b128, 0, stream>>>(x, Wbeta, Wf2, f1, qraw, kraw, vraw, sb);
    scan_kernel<<<256, b256, 0, stream>>>(sb, ov);
    post_kernel<<<32768, b128, 0, stream>>>(ov, og1, Wog2, normw, ybf);

    gemm_bf16<<<dim3(8, 32), b256, 0, stream>>>(ybf, WoT, out, 4096, 1024, 1024);
}